// Round 1
// baseline (2871.907 us; speedup 1.0000x reference)
//
#include <hip/hip_runtime.h>
#include <cstddef>

// Problem constants (fixed by setup_inputs)
#define B_  4
#define L_  2048
#define D_  768
#define NH_ 12
#define HD_ 64
#define M_  (B_*L_)   // 8192 rows

// ---------------------------------------------------------------------------
// GEMM: Y[m,n] = sum_k A[m,k]*W[n,k] (+ bias[n]) (+ resid[m,n])
// A:[M,K] row-major, W:[N,K] row-major (torch Linear weight), both read
// row-wise => coalesced "NT" GEMM. 64x64 tile, 256 thr, 4x4 micro-tile.
// ---------------------------------------------------------------------------
__global__ __launch_bounds__(256) void gemm_nt_kernel(
    const float* __restrict__ A, const float* __restrict__ W,
    const float* __restrict__ bias, const float* __restrict__ resid,
    float* __restrict__ Y, int M, int N, int K)
{
    __shared__ float As[16][65];   // [k][m], +1 pad
    __shared__ float Ws[16][65];   // [k][n]
    const int tid = threadIdx.x;
    const int tx = tid & 15, ty = tid >> 4;
    const int bm = blockIdx.y * 64, bn = blockIdx.x * 64;
    float acc[4][4] = {};
    for (int k0 = 0; k0 < K; k0 += 16) {
        #pragma unroll
        for (int i = tid; i < 1024; i += 256) {
            int r = i >> 4, c = i & 15;
            As[c][r] = A[(size_t)(bm + r) * K + k0 + c];
            Ws[c][r] = W[(size_t)(bn + r) * K + k0 + c];
        }
        __syncthreads();
        #pragma unroll
        for (int kk = 0; kk < 16; ++kk) {
            float a[4], b[4];
            #pragma unroll
            for (int i = 0; i < 4; ++i) a[i] = As[kk][ty * 4 + i];
            #pragma unroll
            for (int j = 0; j < 4; ++j) b[j] = Ws[kk][tx * 4 + j];
            #pragma unroll
            for (int i = 0; i < 4; ++i)
                #pragma unroll
                for (int j = 0; j < 4; ++j)
                    acc[i][j] = fmaf(a[i], b[j], acc[i][j]);
        }
        __syncthreads();
    }
    #pragma unroll
    for (int i = 0; i < 4; ++i) {
        int row = bm + ty * 4 + i;
        #pragma unroll
        for (int j = 0; j < 4; ++j) {
            int col = bn + tx * 4 + j;
            float y = acc[i][j];
            if (bias)  y += bias[col];
            if (resid) y += resid[(size_t)row * N + col];
            Y[(size_t)row * N + col] = y;
        }
    }
}

// ---------------------------------------------------------------------------
// Row LayerNorm (no bias) * gamma, in place. One block per row of 768.
// jnp.var => population variance (ddof=0), eps = 1e-5.
// ---------------------------------------------------------------------------
__global__ __launch_bounds__(256) void ln_kernel(float* __restrict__ X,
                                                 const float* __restrict__ gamma)
{
    const int row = blockIdx.x;
    float* x = X + (size_t)row * D_;
    const int tid = threadIdx.x;
    float v[3];
    float lsum = 0.f, lsq = 0.f;
    #pragma unroll
    for (int e = 0; e < 3; ++e) {
        float t = x[tid + e * 256];
        v[e] = t; lsum += t; lsq += t * t;
    }
    #pragma unroll
    for (int off = 32; off > 0; off >>= 1) {
        lsum += __shfl_down(lsum, off);
        lsq  += __shfl_down(lsq,  off);
    }
    __shared__ float s1[4], s2[4];
    const int wave = tid >> 6, lane = tid & 63;
    if (lane == 0) { s1[wave] = lsum; s2[wave] = lsq; }
    __syncthreads();
    const float sum = s1[0] + s1[1] + s1[2] + s1[3];
    const float sq  = s2[0] + s2[1] + s2[2] + s2[3];
    const float mu  = sum * (1.0f / D_);
    const float var = sq * (1.0f / D_) - mu * mu;
    const float inv = rsqrtf(var + 1e-5f);
    #pragma unroll
    for (int e = 0; e < 3; ++e) {
        int c = tid + e * 256;
        x[c] = (v[e] - mu) * inv * gamma[c];
    }
}

// ---------------------------------------------------------------------------
// Pass A: per-key softmax stats over the QUERY axis.
// s[q,k] = (q_row . k_row) * 0.125 ; m[k] = max_q s ; l[k] = sum_q exp(s-m)
// Block = one 64-key tile of one (b,head); loops all 2048 queries.
// ---------------------------------------------------------------------------
__global__ __launch_bounds__(256) void attn_stats_kernel(
    const float* __restrict__ Q, const float* __restrict__ Kb,
    float* __restrict__ Ms, float* __restrict__ Ls)
{
    const int bn = blockIdx.y;               // 0..47
    const int b = bn / NH_, h = bn % NH_;
    const int kbase = blockIdx.x * 64;
    const float* Qh = Q  + (size_t)b * L_ * D_ + h * HD_;
    const float* Kh = Kb + (size_t)b * L_ * D_ + h * HD_;
    __shared__ float Ks[64][65];
    __shared__ float Qs[64][65];
    __shared__ float Ss[64][65];
    __shared__ float mrun[64], lrun[64];
    const int tid = threadIdx.x;
    const int tx = tid & 15, ty = tid >> 4;
    for (int i = tid; i < 4096; i += 256) {
        int r = i >> 6, c = i & 63;
        Ks[r][c] = Kh[(size_t)(kbase + r) * D_ + c];
    }
    if (tid < 64) { mrun[tid] = -1e30f; lrun[tid] = 0.f; }
    __syncthreads();
    for (int q0 = 0; q0 < L_; q0 += 64) {
        for (int i = tid; i < 4096; i += 256) {
            int r = i >> 6, c = i & 63;
            Qs[r][c] = Qh[(size_t)(q0 + r) * D_ + c];
        }
        __syncthreads();
        float acc[4][4] = {};
        #pragma unroll 8
        for (int d = 0; d < 64; ++d) {
            float a[4], bb[4];
            #pragma unroll
            for (int i = 0; i < 4; ++i) a[i]  = Qs[ty * 4 + i][d];
            #pragma unroll
            for (int j = 0; j < 4; ++j) bb[j] = Ks[tx * 4 + j][d];
            #pragma unroll
            for (int i = 0; i < 4; ++i)
                #pragma unroll
                for (int j = 0; j < 4; ++j)
                    acc[i][j] = fmaf(a[i], bb[j], acc[i][j]);
        }
        #pragma unroll
        for (int i = 0; i < 4; ++i)
            #pragma unroll
            for (int j = 0; j < 4; ++j)
                Ss[ty * 4 + i][tx * 4 + j] = acc[i][j] * 0.125f;
        __syncthreads();
        if (tid < 64) {
            float m_old = mrun[tid];
            float mc = m_old;
            #pragma unroll 8
            for (int q = 0; q < 64; ++q) mc = fmaxf(mc, Ss[q][tid]);
            float l = lrun[tid] * __expf(m_old - mc);
            #pragma unroll 8
            for (int q = 0; q < 64; ++q) l += __expf(Ss[q][tid] - mc);
            mrun[tid] = mc; lrun[tid] = l;
        }
        __syncthreads();
    }
    if (tid < 64) {
        Ms[(size_t)bn * L_ + kbase + tid] = mrun[tid];
        Ls[(size_t)bn * L_ + kbase + tid] = lrun[tid];
    }
}

// ---------------------------------------------------------------------------
// Pass B: o[q,d] = sum_k exp(s[q,k]-m[k])/l[k] * v[k,d]
// Block = one 64-query tile of one (b,head); loops all 2048 keys.
// Writes o OVER the q buffer (safe: block's q rows live in LDS).
// ---------------------------------------------------------------------------
__global__ __launch_bounds__(256) void attn_out_kernel(
    const float* __restrict__ Q, const float* __restrict__ Kb,
    const float* __restrict__ V,
    const float* __restrict__ Ms, const float* __restrict__ Ls,
    float* __restrict__ O)
{
    const int bn = blockIdx.y;
    const int b = bn / NH_, h = bn % NH_;
    const int qbase = blockIdx.x * 64;
    const float* Qh = Q  + (size_t)b * L_ * D_ + h * HD_;
    const float* Kh = Kb + (size_t)b * L_ * D_ + h * HD_;
    const float* Vh = V  + (size_t)b * L_ * D_ + h * HD_;
    __shared__ float Qs[64][65];
    __shared__ float Ks[64][65];
    __shared__ float Vs[64][64];
    __shared__ float Ps[64][65];
    __shared__ float mch[64], lch[64];
    const int tid = threadIdx.x;
    const int tx = tid & 15, ty = tid >> 4;
    for (int i = tid; i < 4096; i += 256) {
        int r = i >> 6, c = i & 63;
        Qs[r][c] = Qh[(size_t)(qbase + r) * D_ + c];
    }
    float acco[16] = {};
    const int qo = tid >> 2;            // 0..63: query row this thread owns for o
    const int dbase = (tid & 3) * 16;   // 16 dims
    for (int k0 = 0; k0 < L_; k0 += 64) {
        for (int i = tid; i < 4096; i += 256) {
            int r = i >> 6, c = i & 63;
            Ks[r][c] = Kh[(size_t)(k0 + r) * D_ + c];
            Vs[r][c] = Vh[(size_t)(k0 + r) * D_ + c];
        }
        if (tid < 64) {
            mch[tid] = Ms[(size_t)bn * L_ + k0 + tid];
            lch[tid] = Ls[(size_t)bn * L_ + k0 + tid];
        }
        __syncthreads();
        float acc[4][4] = {};
        #pragma unroll 8
        for (int d = 0; d < 64; ++d) {
            float a[4], bb[4];
            #pragma unroll
            for (int i = 0; i < 4; ++i) a[i]  = Qs[ty * 4 + i][d];
            #pragma unroll
            for (int j = 0; j < 4; ++j) bb[j] = Ks[tx * 4 + j][d];
            #pragma unroll
            for (int i = 0; i < 4; ++i)
                #pragma unroll
                for (int j = 0; j < 4; ++j)
                    acc[i][j] = fmaf(a[i], bb[j], acc[i][j]);
        }
        #pragma unroll
        for (int j = 0; j < 4; ++j) {
            int kk = tx * 4 + j;
            float m = mch[kk], il = 1.0f / lch[kk];
            #pragma unroll
            for (int i = 0; i < 4; ++i)
                Ps[ty * 4 + i][kk] = __expf(acc[i][j] * 0.125f - m) * il;
        }
        __syncthreads();
        #pragma unroll 8
        for (int kk = 0; kk < 64; ++kk) {
            float p = Ps[qo][kk];
            #pragma unroll
            for (int e = 0; e < 16; ++e)
                acco[e] = fmaf(p, Vs[kk][dbase + e], acco[e]);
        }
        __syncthreads();
    }
    float* orow = O + (size_t)b * L_ * D_ + (size_t)(qbase + qo) * D_ + h * HD_ + dbase;
    #pragma unroll
    for (int e = 0; e < 16; ++e) orow[e] = acco[e];
}

// ---------------------------------------------------------------------------
extern "C" void kernel_launch(void* const* d_in, const int* in_sizes, int n_in,
                              void* d_out, int out_size, void* d_ws, size_t ws_size,
                              hipStream_t stream)
{
    const float* x  = (const float*)d_in[0];
    const float* Wq = (const float*)d_in[1];
    const float* Wk = (const float*)d_in[2];
    const float* bk = (const float*)d_in[3];
    const float* Wv = (const float*)d_in[4];
    const float* bv = (const float*)d_in[5];
    const float* gq = (const float*)d_in[6];
    const float* gk = (const float*)d_in[7];
    const float* Wo = (const float*)d_in[8];
    const float* bo = (const float*)d_in[9];
    float* out = (float*)d_out;

    // workspace layout: q | k | v | m | l   (76.3 MB)
    float* q  = (float*)d_ws;
    float* k  = q  + (size_t)M_ * D_;
    float* v  = k  + (size_t)M_ * D_;
    float* ms = v  + (size_t)M_ * D_;
    float* ls = ms + (size_t)B_ * NH_ * L_;

    dim3 gblk(256);
    dim3 ggrid(D_ / 64, M_ / 64);     // (12, 128)
    // projections
    gemm_nt_kernel<<<ggrid, gblk, 0, stream>>>(x, Wq, nullptr, nullptr, q, M_, D_, D_);
    gemm_nt_kernel<<<ggrid, gblk, 0, stream>>>(x, Wk, bk,      nullptr, k, M_, D_, D_);
    gemm_nt_kernel<<<ggrid, gblk, 0, stream>>>(x, Wv, bv,      nullptr, v, M_, D_, D_);
    // QK layernorm (in place)
    ln_kernel<<<dim3(M_), gblk, 0, stream>>>(q, gq);
    ln_kernel<<<dim3(M_), gblk, 0, stream>>>(k, gk);
    // attention: per-key softmax stats, then output (o overwrites q)
    dim3 agrid(L_ / 64, B_ * NH_);    // (32, 48)
    attn_stats_kernel<<<agrid, gblk, 0, stream>>>(q, k, ms, ls);
    attn_out_kernel<<<agrid, gblk, 0, stream>>>(q, k, v, ms, ls, q);
    // output projection + bias + residual
    gemm_nt_kernel<<<ggrid, gblk, 0, stream>>>(q, Wo, bo, x, out, M_, D_, D_);
}

// Round 3
// 424.152 us; speedup vs baseline: 6.7709x; 6.7709x over previous
//
#include <hip/hip_runtime.h>
#include <cstddef>
#include <cstdint>

// ---------------------------------------------------------------------------
// MultiheadSelfAttn (b=4, l=2048, d=768, nh=12, hd=64), softmax over QUERY axis.
// bf16-MFMA pipeline: cvt -> 3 proj GEMMs -> LN(->bf16) -> V transpose ->
// per-key softmax stats (pass A) -> attention out (pass B) -> final GEMM.
// All MFMA accumulation fp32; softmax in exp2 domain (v_exp_f32 via builtin).
// ---------------------------------------------------------------------------

typedef unsigned short u16;
typedef short  bf16x8 __attribute__((ext_vector_type(8)));   // 4 VGPRs: MFMA A/B frag
typedef float  f32x4  __attribute__((ext_vector_type(4)));   // MFMA C/D frag
typedef unsigned short u16x8 __attribute__((ext_vector_type(8)));
typedef unsigned short u16x4 __attribute__((ext_vector_type(4)));

#define B_   4
#define L_   2048
#define D_   768
#define NH_  12
#define HD_  64
#define M_   (B_*L_)
// scale * log2(e): softmax computed in exp2 domain (consistent between passes)
#define SC2  (0.125f * 1.44269504088896f)

// exp2 via v_exp_f32 (avoid __exp2f: glibc macro collision)
__device__ __forceinline__ float ex2(float x) {
    return __builtin_amdgcn_exp2f(x);
}

__device__ __forceinline__ u16 f2bf(float f) {
    union { float f; unsigned u; } v; v.f = f;
    unsigned r = v.u + 0x7FFFu + ((v.u >> 16) & 1u);   // RNE
    return (u16)(r >> 16);
}

// async global->LDS, 16B per lane. lds ptr must be wave-uniform base;
// HW writes base + lane*16.
__device__ __forceinline__ void gld16(const void* g, void* l) {
    __builtin_amdgcn_global_load_lds(
        (const __attribute__((address_space(1))) unsigned*)g,
        (__attribute__((address_space(3))) unsigned*)l, 16, 0, 0);
}

// ---------------------------------------------------------------------------
// fp32 -> bf16 bulk convert (n multiple of 2048)
// ---------------------------------------------------------------------------
__global__ __launch_bounds__(256) void cvt_bf16_kernel(
    const float* __restrict__ X, u16* __restrict__ Y, int n8)
{
    int i = blockIdx.x * 256 + threadIdx.x;
    if (i >= n8) return;
    const float4* xp = (const float4*)X + (size_t)i * 2;
    float4 a = xp[0], b = xp[1];
    u16x8 o;
    o[0] = f2bf(a.x); o[1] = f2bf(a.y); o[2] = f2bf(a.z); o[3] = f2bf(a.w);
    o[4] = f2bf(b.x); o[5] = f2bf(b.y); o[6] = f2bf(b.z); o[7] = f2bf(b.w);
    *((u16x8*)Y + i) = o;
}

// ---------------------------------------------------------------------------
// bf16 NT GEMM: Y[m,n] = sum_k A[m,k]*W[n,k] (+bias) (+resid), out fp32 or bf16
// 128x128 tile, BK=32, 256 thr (4 waves, each 64x64 = 4x4 MFMA 16x16x32).
// ---------------------------------------------------------------------------
__global__ __launch_bounds__(256) void gemm_bf16(
    const u16* __restrict__ A, const u16* __restrict__ W,
    const float* __restrict__ bias, const float* __restrict__ resid,
    float* __restrict__ outf, u16* __restrict__ outb,
    int M, int N, int K)
{
    __shared__ __align__(16) u16 As[128 * 32];
    __shared__ __align__(16) u16 Bs[128 * 32];
    const int tid  = threadIdx.x;
    const int lane = tid & 63, w = tid >> 6;
    const int s    = lane & 15, quad = lane >> 4;
    const int bm   = blockIdx.y * 128, bn = blockIdx.x * 128;
    const int mh   = (w >> 1) * 64, nh = (w & 1) * 64;
    const int wb   = tid & ~63;       // wave-uniform chunk base
    f32x4 acc[4][4];
    #pragma unroll
    for (int i = 0; i < 4; ++i)
        #pragma unroll
        for (int j = 0; j < 4; ++j) acc[i][j] = (f32x4){0.f, 0.f, 0.f, 0.f};

    for (int k0 = 0; k0 < K; k0 += 32) {
        // stage A,B tiles: 512 chunks of 16B each (2 per thread per matrix)
        {
            int c = tid, r = c >> 2, cc = c & 3;
            gld16(A + (size_t)(bm + r) * K + k0 + cc * 8, As + (size_t)wb * 8);
            gld16(W + (size_t)(bn + r) * K + k0 + cc * 8, Bs + (size_t)wb * 8);
            c = tid + 256; r = c >> 2; cc = c & 3;
            gld16(A + (size_t)(bm + r) * K + k0 + cc * 8, As + (size_t)(wb + 256) * 8);
            gld16(W + (size_t)(bn + r) * K + k0 + cc * 8, Bs + (size_t)(wb + 256) * 8);
        }
        __syncthreads();
        bf16x8 af[4], bf[4];
        #pragma unroll
        for (int i = 0; i < 4; ++i)
            af[i] = *(const bf16x8*)(As + (mh + i * 16 + s) * 32 + quad * 8);
        #pragma unroll
        for (int j = 0; j < 4; ++j)
            bf[j] = *(const bf16x8*)(Bs + (nh + j * 16 + s) * 32 + quad * 8);
        #pragma unroll
        for (int i = 0; i < 4; ++i)
            #pragma unroll
            for (int j = 0; j < 4; ++j)
                acc[i][j] = __builtin_amdgcn_mfma_f32_16x16x32_bf16(
                    af[i], bf[j], acc[i][j], 0, 0, 0);
        __syncthreads();
    }
    // epilogue: C layout col=lane&15, row=quad*4+reg
    #pragma unroll
    for (int j = 0; j < 4; ++j) {
        const int n = bn + nh + j * 16 + s;
        const float bb = bias ? bias[n] : 0.0f;
        #pragma unroll
        for (int i = 0; i < 4; ++i) {
            const int m0 = bm + mh + i * 16 + quad * 4;
            #pragma unroll
            for (int r = 0; r < 4; ++r) {
                float y = acc[i][j][r] + bb;
                const size_t idx = (size_t)(m0 + r) * N + n;
                if (resid) y += resid[idx];
                if (outb) outb[idx] = f2bf(y);
                else      outf[idx] = y;
            }
        }
    }
}

// ---------------------------------------------------------------------------
// Row LayerNorm (pop var, eps 1e-5) * gamma, fp32 in -> bf16 out.
// ---------------------------------------------------------------------------
__global__ __launch_bounds__(256) void ln_bf16(
    const float* __restrict__ X, const float* __restrict__ gamma,
    u16* __restrict__ Y)
{
    const int row = blockIdx.x;
    const float* x = X + (size_t)row * D_;
    const int tid = threadIdx.x;
    float v[3];
    float lsum = 0.f, lsq = 0.f;
    #pragma unroll
    for (int e = 0; e < 3; ++e) {
        float t = x[tid + e * 256];
        v[e] = t; lsum += t; lsq += t * t;
    }
    #pragma unroll
    for (int off = 32; off > 0; off >>= 1) {
        lsum += __shfl_down(lsum, off);
        lsq  += __shfl_down(lsq,  off);
    }
    __shared__ float s1[4], s2[4];
    const int wv = tid >> 6, lane = tid & 63;
    if (lane == 0) { s1[wv] = lsum; s2[wv] = lsq; }
    __syncthreads();
    const float sum = s1[0] + s1[1] + s1[2] + s1[3];
    const float sq  = s2[0] + s2[1] + s2[2] + s2[3];
    const float mu  = sum * (1.0f / D_);
    const float var = sq * (1.0f / D_) - mu * mu;
    const float inv = rsqrtf(var + 1e-5f);
    #pragma unroll
    for (int e = 0; e < 3; ++e) {
        int c = tid + e * 256;
        Y[(size_t)row * D_ + c] = f2bf((v[e] - mu) * inv * gamma[c]);
    }
}

// ---------------------------------------------------------------------------
// V transpose: vb[8192][768] bf16 -> vt[48][64][2048] (per-head d-major)
// grid (32 l-tiles, 12 heads, 4 batch), 64x64 LDS tile.
// ---------------------------------------------------------------------------
__global__ __launch_bounds__(256) void transpose_v(
    const u16* __restrict__ Vb, u16* __restrict__ Vt)
{
    const int l0 = blockIdx.x * 64, h = blockIdx.y, b = blockIdx.z;
    __shared__ __align__(16) u16 Ts[64][72];
    const int tid = threadIdx.x;
    #pragma unroll
    for (int c = tid; c < 512; c += 256) {
        int r = c >> 3, cc = c & 7;
        u16x8 val = *(const u16x8*)(Vb + (size_t)(b * L_ + l0 + r) * D_ + h * HD_ + cc * 8);
        *(u16x8*)(&Ts[r][cc * 8]) = val;
    }
    __syncthreads();
    const int d = tid >> 2, lc = (tid & 3) * 16;
    u16 tmp[16];
    #pragma unroll
    for (int e = 0; e < 16; ++e) tmp[e] = Ts[lc + e][d];
    u16x8 o0, o1;
    #pragma unroll
    for (int e = 0; e < 8; ++e) { o0[e] = tmp[e]; o1[e] = tmp[8 + e]; }
    u16* dst = Vt + ((size_t)(b * NH_ + h) * HD_ + d) * L_ + l0 + lc;
    *(u16x8*)dst = o0;
    *(u16x8*)(dst + 8) = o1;
}

// ---------------------------------------------------------------------------
// Pass A: per-key softmax stats (max + sum over QUERY axis), exp2 domain.
// S^T orientation: M=keys, N=queries (both operands native K-major NT).
// Block: 128 keys of one (b,h); loops queries in steps of 128.
// Per-lane running stats (no in-loop shuffles); merged once at the end.
// ---------------------------------------------------------------------------
__global__ __launch_bounds__(256) void attn_stats(
    const u16* __restrict__ Qb, const u16* __restrict__ Kb,
    float* __restrict__ Ms, float* __restrict__ Rl)
{
    __shared__ __align__(16) u16 Ks[128 * 64];
    __shared__ __align__(16) u16 Qs[128 * 64];
    __shared__ float mbuf[4][64];
    __shared__ float lbuf[4][64];
    const int tid  = threadIdx.x;
    const int lane = tid & 63, w = tid >> 6;
    const int s    = lane & 15, quad = lane >> 4;
    const int bh   = blockIdx.y;
    const int b    = bh / NH_, h = bh % NH_;
    const int kbase = blockIdx.x * 128;
    const u16* Qg = Qb + (size_t)b * L_ * D_ + h * HD_;
    const u16* Kg = Kb + (size_t)b * L_ * D_ + h * HD_;
    const int mh = (w >> 1) * 64;   // key half for S^T
    const int nh = (w & 1) * 64;    // query half
    const int wb = tid & ~63;

    // stage K tile once: 1024 x 16B chunks (8 chunks per 64-elem row)
    #pragma unroll
    for (int c0 = 0; c0 < 1024; c0 += 256) {
        int c = c0 + tid, r = c >> 3, cc = c & 7;
        gld16(Kg + (size_t)(kbase + r) * D_ + cc * 8, Ks + (size_t)(c0 + wb) * 8);
    }
    float mrun[4][4], lrun[4][4];
    #pragma unroll
    for (int i = 0; i < 4; ++i)
        #pragma unroll
        for (int r = 0; r < 4; ++r) { mrun[i][r] = -1e30f; lrun[i][r] = 0.f; }

    for (int q0 = 0; q0 < L_; q0 += 128) {
        #pragma unroll
        for (int c0 = 0; c0 < 1024; c0 += 256) {
            int c = c0 + tid, r = c >> 3, cc = c & 7;
            gld16(Qg + (size_t)(q0 + r) * D_ + cc * 8, Qs + (size_t)(c0 + wb) * 8);
        }
        __syncthreads();
        f32x4 acc[4][4];
        #pragma unroll
        for (int i = 0; i < 4; ++i)
            #pragma unroll
            for (int j = 0; j < 4; ++j) acc[i][j] = (f32x4){0.f, 0.f, 0.f, 0.f};
        #pragma unroll
        for (int kk = 0; kk < 2; ++kk) {
            bf16x8 af[4], bf[4];
            #pragma unroll
            for (int i = 0; i < 4; ++i)
                af[i] = *(const bf16x8*)(Ks + (mh + i * 16 + s) * 64 + kk * 32 + quad * 8);
            #pragma unroll
            for (int j = 0; j < 4; ++j)
                bf[j] = *(const bf16x8*)(Qs + (nh + j * 16 + s) * 64 + kk * 32 + quad * 8);
            #pragma unroll
            for (int i = 0; i < 4; ++i)
                #pragma unroll
                for (int j = 0; j < 4; ++j)
                    acc[i][j] = __builtin_amdgcn_mfma_f32_16x16x32_bf16(
                        af[i], bf[j], acc[i][j], 0, 0, 0);
        }
        __syncthreads();   // Qs consumed; stats below are register-only
        // per-lane online update (this lane's query subset only)
        #pragma unroll
        for (int i = 0; i < 4; ++i) {
            #pragma unroll
            for (int r = 0; r < 4; ++r) {
                float t0 = acc[i][0][r] * SC2, t1 = acc[i][1][r] * SC2;
                float t2 = acc[i][2][r] * SC2, t3 = acc[i][3][r] * SC2;
                float cm = fmaxf(fmaxf(t0, t1), fmaxf(t2, t3));
                float mnew = fmaxf(mrun[i][r], cm);
                float ps = ex2(t0 - mnew) + ex2(t1 - mnew)
                         + ex2(t2 - mnew) + ex2(t3 - mnew);
                lrun[i][r] = lrun[i][r] * ex2(mrun[i][r] - mnew) + ps;
                mrun[i][r] = mnew;
            }
        }
    }
    // butterfly-merge the 16 s-lanes (query subsets) within each quad
    #pragma unroll
    for (int i = 0; i < 4; ++i) {
        #pragma unroll
        for (int r = 0; r < 4; ++r) {
            float m = mrun[i][r], l = lrun[i][r];
            #pragma unroll
            for (int d = 1; d < 16; d <<= 1) {
                float om = __shfl_xor(m, d);
                float ol = __shfl_xor(l, d);
                float mn = fmaxf(m, om);
                l = l * ex2(m - mn) + ol * ex2(om - mn);
                m = mn;
            }
            mrun[i][r] = m; lrun[i][r] = l;
        }
    }
    if (s == 0) {
        #pragma unroll
        for (int i = 0; i < 4; ++i)
            #pragma unroll
            for (int r = 0; r < 4; ++r) {
                mbuf[w][i * 16 + quad * 4 + r] = mrun[i][r];
                lbuf[w][i * 16 + quad * 4 + r] = lrun[i][r];
            }
    }
    __syncthreads();
    // merge wave pairs (same keys, complementary query halves), store m & 1/l
    if (tid < 128) {
        int half = tid >> 6, kl = tid & 63;
        float m0 = mbuf[half * 2][kl],     l0 = lbuf[half * 2][kl];
        float m1 = mbuf[half * 2 + 1][kl], l1 = lbuf[half * 2 + 1][kl];
        float m = fmaxf(m0, m1);
        float l = l0 * ex2(m0 - m) + l1 * ex2(m1 - m);
        Ms[(size_t)bh * L_ + kbase + tid] = m;
        Rl[(size_t)bh * L_ + kbase + tid] = 1.0f / l;
    }
}

// ---------------------------------------------------------------------------
// Pass B: O = P·V with P[q,k] = exp2(S2[q,k] - m[k]) * rl[k].
// Block: 128 queries of one (b,h); loops keys in steps of 64.
// S^T (M=keys) -> P^T to LDS (packed b64) -> O^T = V^T·P^T (all-b128 frags).
// O^T round-trips LDS (reusing Pqk) for coalesced bf16 stores.
// ---------------------------------------------------------------------------
__global__ __launch_bounds__(256) void attn_out(
    const u16* __restrict__ Qb, const u16* __restrict__ Kb,
    const u16* __restrict__ Vt,
    const float* __restrict__ Ms, const float* __restrict__ Rl,
    u16* __restrict__ Ob)
{
    __shared__ __align__(16) u16 Qs[128 * 64];   // 16 KB
    __shared__ __align__(16) u16 Ks[64 * 64];    //  8 KB
    __shared__ __align__(16) u16 Vts[64 * 64];   //  8 KB
    __shared__ __align__(16) u16 Pqk[128 * 72];  // 18 KB, P^T as [q][k], pad 72
    __shared__ __align__(16) float mch[64];
    __shared__ __align__(16) float rlch[64];
    const int tid  = threadIdx.x;
    const int lane = tid & 63, w = tid >> 6;
    const int s    = lane & 15, quad = lane >> 4;
    const int bh   = blockIdx.y;
    const int b    = bh / NH_, h = bh % NH_;
    const int qbase = blockIdx.x * 128;
    const u16* Qg  = Qb + (size_t)b * L_ * D_ + h * HD_;
    const u16* Kg  = Kb + (size_t)b * L_ * D_ + h * HD_;
    const u16* Vg  = Vt + (size_t)bh * HD_ * L_;   // [64 d][2048 l]
    const int qh  = (w >> 1) * 64;   // query half (both phases)
    const int kh2 = (w & 1) * 32;    // key sub-tile (S phase)
    const int dh  = (w & 1) * 32;    // d sub-tile (PV phase)
    const int wb  = tid & ~63;

    // stage Q tile once: 1024 chunks
    #pragma unroll
    for (int c0 = 0; c0 < 1024; c0 += 256) {
        int c = c0 + tid, r = c >> 3, cc = c & 7;
        gld16(Qg + (size_t)(qbase + r) * D_ + cc * 8, Qs + (size_t)(c0 + wb) * 8);
    }
    f32x4 acc_o[2][4];
    #pragma unroll
    for (int i = 0; i < 2; ++i)
        #pragma unroll
        for (int j = 0; j < 4; ++j) acc_o[i][j] = (f32x4){0.f, 0.f, 0.f, 0.f};

    for (int k0 = 0; k0 < L_; k0 += 64) {
        // stage K (rows k, 64 d) and V^T (rows d, 64 k): 512 chunks each
        {
            int c = tid, r = c >> 3, cc = c & 7;
            gld16(Kg + (size_t)(k0 + r) * D_ + cc * 8, Ks + (size_t)wb * 8);
            gld16(Vg + (size_t)r * L_ + k0 + cc * 8,   Vts + (size_t)wb * 8);
            c = tid + 256; r = c >> 3; cc = c & 7;
            gld16(Kg + (size_t)(k0 + r) * D_ + cc * 8, Ks + (size_t)(wb + 256) * 8);
            gld16(Vg + (size_t)r * L_ + k0 + cc * 8,   Vts + (size_t)(wb + 256) * 8);
        }
        if (tid < 64)       mch[tid]       = Ms[(size_t)bh * L_ + k0 + tid];
        else if (tid < 128) rlch[tid - 64] = Rl[(size_t)bh * L_ + k0 + tid - 64];
        __syncthreads();
        // ---- S^T phase: 32 keys x 64 queries per wave ----
        f32x4 acc_s[2][4];
        #pragma unroll
        for (int i = 0; i < 2; ++i)
            #pragma unroll
            for (int j = 0; j < 4; ++j) acc_s[i][j] = (f32x4){0.f, 0.f, 0.f, 0.f};
        #pragma unroll
        for (int kk = 0; kk < 2; ++kk) {
            bf16x8 af[2], bf[4];
            #pragma unroll
            for (int i = 0; i < 2; ++i)
                af[i] = *(const bf16x8*)(Ks + (kh2 + i * 16 + s) * 64 + kk * 32 + quad * 8);
            #pragma unroll
            for (int j = 0; j < 4; ++j)
                bf[j] = *(const bf16x8*)(Qs + (qh + j * 16 + s) * 64 + kk * 32 + quad * 8);
            #pragma unroll
            for (int i = 0; i < 2; ++i)
                #pragma unroll
                for (int j = 0; j < 4; ++j)
                    acc_s[i][j] = __builtin_amdgcn_mfma_f32_16x16x32_bf16(
                        af[i], bf[j], acc_s[i][j], 0, 0, 0);
        }
        // ---- P^T = exp2(S2 - m) * rl, write to Pqk[q][k] (b64 packed) ----
        #pragma unroll
        for (int i = 0; i < 2; ++i) {
            const int kb_ = kh2 + i * 16 + quad * 4;
            f32x4 mv  = *(const f32x4*)(mch  + kb_);
            f32x4 rlv = *(const f32x4*)(rlch + kb_);
            #pragma unroll
            for (int j = 0; j < 4; ++j) {
                const int q = qh + j * 16 + s;
                u16x4 pk;
                #pragma unroll
                for (int r = 0; r < 4; ++r)
                    pk[r] = f2bf(ex2(acc_s[i][j][r] * SC2 - mv[r]) * rlv[r]);
                *(u16x4*)(Pqk + q * 72 + kb_) = pk;
            }
        }
        __syncthreads();   // Pqk complete; S reads of Ks done
        // ---- O^T += V^T · P^T : 32 d x 64 q per wave ----
        #pragma unroll
        for (int kk = 0; kk < 2; ++kk) {
            bf16x8 av[2], bp[4];
            #pragma unroll
            for (int i = 0; i < 2; ++i)
                av[i] = *(const bf16x8*)(Vts + (dh + i * 16 + s) * 64 + kk * 32 + quad * 8);
            #pragma unroll
            for (int j = 0; j < 4; ++j)
                bp[j] = *(const bf16x8*)(Pqk + (qh + j * 16 + s) * 72 + kk * 32 + quad * 8);
            #pragma unroll
            for (int i = 0; i < 2; ++i)
                #pragma unroll
                for (int j = 0; j < 4; ++j)
                    acc_o[i][j] = __builtin_amdgcn_mfma_f32_16x16x32_bf16(
                        av[i], bp[j], acc_o[i][j], 0, 0, 0);
        }
        __syncthreads();   // PV reads done before next staging overwrites
    }
    // ---- epilogue: O^T -> LDS (reuse Pqk as [q][d], pad 72) -> coalesced store
    #pragma unroll
    for (int i = 0; i < 2; ++i) {
        const int d0 = dh + i * 16 + quad * 4;
        #pragma unroll
        for (int j = 0; j < 4; ++j) {
            const int q = qh + j * 16 + s;
            u16x4 ov;
            #pragma unroll
            for (int r = 0; r < 4; ++r) ov[r] = f2bf(acc_o[i][j][r]);
            *(u16x4*)(Pqk + q * 72 + d0) = ov;
        }
    }
    __syncthreads();
    {
        const int q = tid >> 1, half = tid & 1;
        u16* dst = Ob + (size_t)(b * L_ + qbase + q) * D_ + h * HD_ + half * 32;
        #pragma unroll
        for (int c = 0; c < 4; ++c) {
            u16x8 v = *(const u16x8*)(Pqk + q * 72 + half * 32 + c * 8);
            *(u16x8*)(dst + c * 8) = v;
        }
    }
}

// ---------------------------------------------------------------------------
extern "C" void kernel_launch(void* const* d_in, const int* in_sizes, int n_in,
                              void* d_out, int out_size, void* d_ws, size_t ws_size,
                              hipStream_t stream)
{
    const float* x  = (const float*)d_in[0];
    const float* Wq = (const float*)d_in[1];
    const float* Wk = (const float*)d_in[2];
    const float* bk = (const float*)d_in[3];
    const float* Wv = (const float*)d_in[4];
    const float* bv = (const float*)d_in[5];
    const float* gq = (const float*)d_in[6];
    const float* gk = (const float*)d_in[7];
    const float* Wo = (const float*)d_in[8];
    const float* bo = (const float*)d_in[9];
    float* out = (float*)d_out;

    // workspace layout (~106.2 MB)
    char* p = (char*)d_ws;
    float* q32 = (float*)p;  p += (size_t)M_ * D_ * 4;    // 25.2 MB (ob aliases)
    float* k32 = (float*)p;  p += (size_t)M_ * D_ * 4;    // 25.2 MB (vt aliases)
    u16* xb  = (u16*)p;      p += (size_t)M_ * D_ * 2;
    u16* qb  = (u16*)p;      p += (size_t)M_ * D_ * 2;
    u16* kb  = (u16*)p;      p += (size_t)M_ * D_ * 2;
    u16* vb  = (u16*)p;      p += (size_t)M_ * D_ * 2;
    u16* wqb = (u16*)p;      p += (size_t)D_ * D_ * 2;
    u16* wkb = (u16*)p;      p += (size_t)D_ * D_ * 2;
    u16* wvb = (u16*)p;      p += (size_t)D_ * D_ * 2;
    u16* wob = (u16*)p;      p += (size_t)D_ * D_ * 2;
    float* Ms = (float*)p;   p += (size_t)B_ * NH_ * L_ * 4;
    float* Rl = (float*)p;   p += (size_t)B_ * NH_ * L_ * 4;
    u16* ob = (u16*)q32;     // q32 dead after LN
    u16* vt = (u16*)k32;     // k32 dead after LN

    const int nX = M_ * D_, nW = D_ * D_;
    cvt_bf16_kernel<<<nX / 2048, 256, 0, stream>>>(x,  xb,  nX / 8);
    cvt_bf16_kernel<<<nW / 2048, 256, 0, stream>>>(Wq, wqb, nW / 8);
    cvt_bf16_kernel<<<nW / 2048, 256, 0, stream>>>(Wk, wkb, nW / 8);
    cvt_bf16_kernel<<<nW / 2048, 256, 0, stream>>>(Wv, wvb, nW / 8);
    cvt_bf16_kernel<<<nW / 2048, 256, 0, stream>>>(Wo, wob, nW / 8);

    dim3 ggrid(D_ / 128, M_ / 128);   // (6, 64)
    gemm_bf16<<<ggrid, 256, 0, stream>>>(xb, wqb, nullptr, nullptr, q32, nullptr, M_, D_, D_);
    gemm_bf16<<<ggrid, 256, 0, stream>>>(xb, wkb, bk,      nullptr, k32, nullptr, M_, D_, D_);
    gemm_bf16<<<ggrid, 256, 0, stream>>>(xb, wvb, bv,      nullptr, nullptr, vb,  M_, D_, D_);

    ln_bf16<<<M_, 256, 0, stream>>>(q32, gq, qb);
    ln_bf16<<<M_, 256, 0, stream>>>(k32, gk, kb);

    transpose_v<<<dim3(L_ / 64, NH_, B_), 256, 0, stream>>>(vb, vt);

    dim3 agrid(L_ / 128, B_ * NH_);   // (16, 48)
    attn_stats<<<agrid, 256, 0, stream>>>(qb, kb, Ms, Rl);
    attn_out<<<agrid, 256, 0, stream>>>(qb, kb, vt, Ms, Rl, ob);

    gemm_bf16<<<ggrid, 256, 0, stream>>>(ob, wob, bo, x, out, nullptr, M_, D_, D_);
}

// Round 4
// 338.827 us; speedup vs baseline: 8.4760x; 1.2518x over previous
//
#include <hip/hip_runtime.h>
#include <cstddef>
#include <cstdint>

// ---------------------------------------------------------------------------
// MultiheadSelfAttn (b=4, l=2048, d=768, nh=12, hd=64), softmax over QUERY axis.
// bf16-MFMA pipeline: cvt -> fused QKV GEMM -> LN(->bf16) -> stats ->
// V transpose (*1/l folded) -> attention out -> final GEMM.
// XOR bank-group swizzle on all stride-64 LDS tiles (via source-permuted
// global_load_lds); Q/K fragments hoisted to registers outside k-loops.
// ---------------------------------------------------------------------------

typedef unsigned short u16;
typedef short  bf16x8 __attribute__((ext_vector_type(8)));   // MFMA A/B frag
typedef float  f32x4  __attribute__((ext_vector_type(4)));   // MFMA C/D frag
typedef unsigned short u16x8 __attribute__((ext_vector_type(8)));
typedef unsigned short u16x4 __attribute__((ext_vector_type(4)));

#define B_   4
#define L_   2048
#define D_   768
#define NH_  12
#define HD_  64
#define M_   (B_*L_)
#define SC2  (0.125f * 1.44269504088896f)   // scale * log2(e)

__device__ __forceinline__ float ex2(float x) { return __builtin_amdgcn_exp2f(x); }

__device__ __forceinline__ u16 f2bf(float f) {            // RNE
    union { float f; unsigned u; } v; v.f = f;
    unsigned r = v.u + 0x7FFFu + ((v.u >> 16) & 1u);
    return (u16)(r >> 16);
}
__device__ __forceinline__ u16 f2bf_ru(float f) {          // round-half-up (cheap)
    union { float f; unsigned u; } v; v.f = f;
    return (u16)((v.u + 0x8000u) >> 16);
}
__device__ __forceinline__ float bf2f(u16 b) {
    union { unsigned u; float f; } v; v.u = ((unsigned)b) << 16;
    return v.f;
}

// async global->LDS, 16B/lane; LDS dest = wave-uniform base + lane*16.
__device__ __forceinline__ void gld16(const void* g, void* l) {
    __builtin_amdgcn_global_load_lds(
        (const __attribute__((address_space(1))) unsigned*)g,
        (__attribute__((address_space(3))) unsigned*)l, 16, 0, 0);
}

// ---------------------------------------------------------------------------
// fp32 -> bf16 bulk convert
// ---------------------------------------------------------------------------
__global__ __launch_bounds__(256) void cvt_bf16_kernel(
    const float* __restrict__ X, u16* __restrict__ Y, int n8)
{
    int i = blockIdx.x * 256 + threadIdx.x;
    if (i >= n8) return;
    const float4* xp = (const float4*)X + (size_t)i * 2;
    float4 a = xp[0], b = xp[1];
    u16x8 o;
    o[0] = f2bf(a.x); o[1] = f2bf(a.y); o[2] = f2bf(a.z); o[3] = f2bf(a.w);
    o[4] = f2bf(b.x); o[5] = f2bf(b.y); o[6] = f2bf(b.z); o[7] = f2bf(b.w);
    *((u16x8*)Y + i) = o;
}

// 4 weight matrices in one dispatch (blockIdx.y selects)
__global__ __launch_bounds__(256) void cvt4_bf16_kernel(
    const float* __restrict__ W0, const float* __restrict__ W1,
    const float* __restrict__ W2, const float* __restrict__ W3,
    u16* __restrict__ Y0, u16* __restrict__ Y1,
    u16* __restrict__ Y2, u16* __restrict__ Y3, int n8)
{
    const float* X; u16* Y;
    switch (blockIdx.y) {
        case 0: X = W0; Y = Y0; break;
        case 1: X = W1; Y = Y1; break;
        case 2: X = W2; Y = Y2; break;
        default: X = W3; Y = Y3; break;
    }
    int i = blockIdx.x * 256 + threadIdx.x;
    if (i >= n8) return;
    const float4* xp = (const float4*)X + (size_t)i * 2;
    float4 a = xp[0], b = xp[1];
    u16x8 o;
    o[0] = f2bf(a.x); o[1] = f2bf(a.y); o[2] = f2bf(a.z); o[3] = f2bf(a.w);
    o[4] = f2bf(b.x); o[5] = f2bf(b.y); o[6] = f2bf(b.z); o[7] = f2bf(b.w);
    *((u16x8*)Y + i) = o;
}

// ---------------------------------------------------------------------------
// Fused QKV GEMM: A[8192,768] x {Wq,Wk,Wv}^T. 128x128 tile, BK=32.
// seg 0 -> q32 (fp32), seg 1 -> k32 (fp32 + bk), seg 2 -> vb (bf16 + bv).
// ---------------------------------------------------------------------------
__global__ __launch_bounds__(256) void gemm_qkv(
    const u16* __restrict__ A,
    const u16* __restrict__ W0, const u16* __restrict__ W1,
    const u16* __restrict__ W2,
    const float* __restrict__ bk, const float* __restrict__ bv,
    float* __restrict__ q32, float* __restrict__ k32, u16* __restrict__ vb)
{
    __shared__ __align__(16) u16 As[128 * 32];
    __shared__ __align__(16) u16 Bs[128 * 32];
    const int tid  = threadIdx.x;
    const int lane = tid & 63, w = tid >> 6;
    const int s    = lane & 15, quad = lane >> 4;
    const int seg  = blockIdx.x / 6;
    const int bn   = (blockIdx.x % 6) * 128;
    const int bm   = blockIdx.y * 128;
    const u16* W = (seg == 0) ? W0 : ((seg == 1) ? W1 : W2);
    const int mh = (w >> 1) * 64, nh = (w & 1) * 64;
    const int wb = tid & ~63;
    f32x4 acc[4][4];
    #pragma unroll
    for (int i = 0; i < 4; ++i)
        #pragma unroll
        for (int j = 0; j < 4; ++j) acc[i][j] = (f32x4){0.f, 0.f, 0.f, 0.f};

    for (int k0 = 0; k0 < D_; k0 += 32) {
        {
            int c = tid, r = c >> 2, cc = c & 3;
            gld16(A + (size_t)(bm + r) * D_ + k0 + cc * 8, As + (size_t)wb * 8);
            gld16(W + (size_t)(bn + r) * D_ + k0 + cc * 8, Bs + (size_t)wb * 8);
            c = tid + 256; r = c >> 2; cc = c & 3;
            gld16(A + (size_t)(bm + r) * D_ + k0 + cc * 8, As + (size_t)(wb + 256) * 8);
            gld16(W + (size_t)(bn + r) * D_ + k0 + cc * 8, Bs + (size_t)(wb + 256) * 8);
        }
        __syncthreads();
        bf16x8 af[4], bf[4];
        #pragma unroll
        for (int i = 0; i < 4; ++i)
            af[i] = *(const bf16x8*)(As + (mh + i * 16 + s) * 32 + quad * 8);
        #pragma unroll
        for (int j = 0; j < 4; ++j)
            bf[j] = *(const bf16x8*)(Bs + (nh + j * 16 + s) * 32 + quad * 8);
        #pragma unroll
        for (int i = 0; i < 4; ++i)
            #pragma unroll
            for (int j = 0; j < 4; ++j)
                acc[i][j] = __builtin_amdgcn_mfma_f32_16x16x32_bf16(
                    af[i], bf[j], acc[i][j], 0, 0, 0);
        __syncthreads();
    }
    #pragma unroll
    for (int j = 0; j < 4; ++j) {
        const int n = bn + nh + j * 16 + s;
        float bb = 0.0f;
        if (seg == 1) bb = bk[n];
        else if (seg == 2) bb = bv[n];
        #pragma unroll
        for (int i = 0; i < 4; ++i) {
            const int m0 = bm + mh + i * 16 + quad * 4;
            #pragma unroll
            for (int r = 0; r < 4; ++r) {
                float y = acc[i][j][r] + bb;
                const size_t idx = (size_t)(m0 + r) * D_ + n;
                if (seg == 0)      q32[idx] = y;
                else if (seg == 1) k32[idx] = y;
                else               vb[idx]  = f2bf(y);
            }
        }
    }
}

// ---------------------------------------------------------------------------
// Final GEMM: out = ob @ Wo^T + bo + x (fp32 out)
// ---------------------------------------------------------------------------
__global__ __launch_bounds__(256) void gemm_final(
    const u16* __restrict__ A, const u16* __restrict__ W,
    const float* __restrict__ bias, const float* __restrict__ resid,
    float* __restrict__ outf)
{
    __shared__ __align__(16) u16 As[128 * 32];
    __shared__ __align__(16) u16 Bs[128 * 32];
    const int tid  = threadIdx.x;
    const int lane = tid & 63, w = tid >> 6;
    const int s    = lane & 15, quad = lane >> 4;
    const int bm   = blockIdx.y * 128, bn = blockIdx.x * 128;
    const int mh   = (w >> 1) * 64, nh = (w & 1) * 64;
    const int wb   = tid & ~63;
    f32x4 acc[4][4];
    #pragma unroll
    for (int i = 0; i < 4; ++i)
        #pragma unroll
        for (int j = 0; j < 4; ++j) acc[i][j] = (f32x4){0.f, 0.f, 0.f, 0.f};

    for (int k0 = 0; k0 < D_; k0 += 32) {
        {
            int c = tid, r = c >> 2, cc = c & 3;
            gld16(A + (size_t)(bm + r) * D_ + k0 + cc * 8, As + (size_t)wb * 8);
            gld16(W + (size_t)(bn + r) * D_ + k0 + cc * 8, Bs + (size_t)wb * 8);
            c = tid + 256; r = c >> 2; cc = c & 3;
            gld16(A + (size_t)(bm + r) * D_ + k0 + cc * 8, As + (size_t)(wb + 256) * 8);
            gld16(W + (size_t)(bn + r) * D_ + k0 + cc * 8, Bs + (size_t)(wb + 256) * 8);
        }
        __syncthreads();
        bf16x8 af[4], bf[4];
        #pragma unroll
        for (int i = 0; i < 4; ++i)
            af[i] = *(const bf16x8*)(As + (mh + i * 16 + s) * 32 + quad * 8);
        #pragma unroll
        for (int j = 0; j < 4; ++j)
            bf[j] = *(const bf16x8*)(Bs + (nh + j * 16 + s) * 32 + quad * 8);
        #pragma unroll
        for (int i = 0; i < 4; ++i)
            #pragma unroll
            for (int j = 0; j < 4; ++j)
                acc[i][j] = __builtin_amdgcn_mfma_f32_16x16x32_bf16(
                    af[i], bf[j], acc[i][j], 0, 0, 0);
        __syncthreads();
    }
    #pragma unroll
    for (int j = 0; j < 4; ++j) {
        const int n = bn + nh + j * 16 + s;
        const float bb = bias[n];
        #pragma unroll
        for (int i = 0; i < 4; ++i) {
            const int m0 = bm + mh + i * 16 + quad * 4;
            #pragma unroll
            for (int r = 0; r < 4; ++r) {
                const size_t idx = (size_t)(m0 + r) * D_ + n;
                outf[idx] = acc[i][j][r] + bb + resid[idx];
            }
        }
    }
}

// ---------------------------------------------------------------------------
// Row LayerNorm (pop var, eps 1e-5) * gamma, fp32 in -> bf16 out.
// ---------------------------------------------------------------------------
__global__ __launch_bounds__(256) void ln_bf16(
    const float* __restrict__ X, const float* __restrict__ gamma,
    u16* __restrict__ Y)
{
    const int row = blockIdx.x;
    const float* x = X + (size_t)row * D_;
    const int tid = threadIdx.x;
    float v[3];
    float lsum = 0.f, lsq = 0.f;
    #pragma unroll
    for (int e = 0; e < 3; ++e) {
        float t = x[tid + e * 256];
        v[e] = t; lsum += t; lsq += t * t;
    }
    #pragma unroll
    for (int off = 32; off > 0; off >>= 1) {
        lsum += __shfl_down(lsum, off);
        lsq  += __shfl_down(lsq,  off);
    }
    __shared__ float s1[4], s2[4];
    const int wv = tid >> 6, lane = tid & 63;
    if (lane == 0) { s1[wv] = lsum; s2[wv] = lsq; }
    __syncthreads();
    const float sum = s1[0] + s1[1] + s1[2] + s1[3];
    const float sq  = s2[0] + s2[1] + s2[2] + s2[3];
    const float mu  = sum * (1.0f / D_);
    const float var = sq * (1.0f / D_) - mu * mu;
    const float inv = rsqrtf(var + 1e-5f);
    #pragma unroll
    for (int e = 0; e < 3; ++e) {
        int c = tid + e * 256;
        Y[(size_t)row * D_ + c] = f2bf((v[e] - mu) * inv * gamma[c]);
    }
}

// ---------------------------------------------------------------------------
// Pass A: per-key softmax stats over QUERY axis (exp2 domain).
// S^T: M=keys(128/block), N=queries (loop 2048 by 128). K frags hoisted.
// XOR source swizzle on K/Q staging; frag reads XOR-matched.
// ---------------------------------------------------------------------------
__global__ __launch_bounds__(256) void attn_stats(
    const u16* __restrict__ Qb, const u16* __restrict__ Kb,
    float* __restrict__ Ms, float* __restrict__ Rl)
{
    __shared__ __align__(16) u16 Ks[128 * 64];
    __shared__ __align__(16) u16 Qs[128 * 64];
    __shared__ float mbuf[4][64];
    __shared__ float lbuf[4][64];
    const int tid  = threadIdx.x;
    const int lane = tid & 63, w = tid >> 6;
    const int s    = lane & 15, quad = lane >> 4;
    const int s7   = s & 7;
    const int bh   = blockIdx.y;
    const int b    = bh / NH_, h = bh % NH_;
    const int kbase = blockIdx.x * 128;
    const u16* Qg = Qb + (size_t)b * L_ * D_ + h * HD_;
    const u16* Kg = Kb + (size_t)b * L_ * D_ + h * HD_;
    const int mh = (w >> 1) * 64;   // key half
    const int nh = (w & 1) * 64;    // query half
    const int wb = tid & ~63;

    // stage K tile once (source-XOR-swizzled)
    #pragma unroll
    for (int c0 = 0; c0 < 1024; c0 += 256) {
        int c = c0 + tid, r = c >> 3, cc = (c & 7) ^ (r & 7);
        gld16(Kg + (size_t)(kbase + r) * D_ + cc * 8, Ks + (size_t)(c0 + wb) * 8);
    }
    __syncthreads();
    // hoist K fragments (loop-invariant)
    bf16x8 kf[2][4];
    #pragma unroll
    for (int kk = 0; kk < 2; ++kk)
        #pragma unroll
        for (int i = 0; i < 4; ++i)
            kf[kk][i] = *(const bf16x8*)(Ks + (mh + i * 16 + s) * 64 +
                                         ((kk * 4 + quad) ^ s7) * 8);

    float mrun[4][4], lrun[4][4];
    #pragma unroll
    for (int i = 0; i < 4; ++i)
        #pragma unroll
        for (int r = 0; r < 4; ++r) { mrun[i][r] = -1e30f; lrun[i][r] = 0.f; }

    for (int q0 = 0; q0 < L_; q0 += 128) {
        #pragma unroll
        for (int c0 = 0; c0 < 1024; c0 += 256) {
            int c = c0 + tid, r = c >> 3, cc = (c & 7) ^ (r & 7);
            gld16(Qg + (size_t)(q0 + r) * D_ + cc * 8, Qs + (size_t)(c0 + wb) * 8);
        }
        __syncthreads();
        f32x4 acc[4][4];
        #pragma unroll
        for (int i = 0; i < 4; ++i)
            #pragma unroll
            for (int j = 0; j < 4; ++j) acc[i][j] = (f32x4){0.f, 0.f, 0.f, 0.f};
        #pragma unroll
        for (int kk = 0; kk < 2; ++kk) {
            bf16x8 bf[4];
            #pragma unroll
            for (int j = 0; j < 4; ++j)
                bf[j] = *(const bf16x8*)(Qs + (nh + j * 16 + s) * 64 +
                                         ((kk * 4 + quad) ^ s7) * 8);
            #pragma unroll
            for (int i = 0; i < 4; ++i)
                #pragma unroll
                for (int j = 0; j < 4; ++j)
                    acc[i][j] = __builtin_amdgcn_mfma_f32_16x16x32_bf16(
                        kf[kk][i], bf[j], acc[i][j], 0, 0, 0);
        }
        __syncthreads();   // Qs reads complete before next staging
        #pragma unroll
        for (int i = 0; i < 4; ++i) {
            #pragma unroll
            for (int r = 0; r < 4; ++r) {
                float a0 = acc[i][0][r], a1 = acc[i][1][r];
                float a2 = acc[i][2][r], a3 = acc[i][3][r];
                float cm = fmaxf(fmaxf(a0, a1), fmaxf(a2, a3));
                float mnew = fmaxf(mrun[i][r], cm * SC2);
                float l = lrun[i][r] * ex2(mrun[i][r] - mnew)
                        + ex2(fmaf(a0, SC2, -mnew)) + ex2(fmaf(a1, SC2, -mnew))
                        + ex2(fmaf(a2, SC2, -mnew)) + ex2(fmaf(a3, SC2, -mnew));
                lrun[i][r] = l; mrun[i][r] = mnew;
            }
        }
    }
    // butterfly-merge the 16 s-lanes within each quad
    #pragma unroll
    for (int i = 0; i < 4; ++i) {
        #pragma unroll
        for (int r = 0; r < 4; ++r) {
            float m = mrun[i][r], l = lrun[i][r];
            #pragma unroll
            for (int d = 1; d < 16; d <<= 1) {
                float om = __shfl_xor(m, d);
                float ol = __shfl_xor(l, d);
                float mn = fmaxf(m, om);
                l = l * ex2(m - mn) + ol * ex2(om - mn);
                m = mn;
            }
            mrun[i][r] = m; lrun[i][r] = l;
        }
    }
    if (s == 0) {
        #pragma unroll
        for (int i = 0; i < 4; ++i)
            #pragma unroll
            for (int r = 0; r < 4; ++r) {
                mbuf[w][i * 16 + quad * 4 + r] = mrun[i][r];
                lbuf[w][i * 16 + quad * 4 + r] = lrun[i][r];
            }
    }
    __syncthreads();
    if (tid < 128) {
        int half = tid >> 6, kl = tid & 63;
        float m0 = mbuf[half * 2][kl],     l0 = lbuf[half * 2][kl];
        float m1 = mbuf[half * 2 + 1][kl], l1 = lbuf[half * 2 + 1][kl];
        float m = fmaxf(m0, m1);
        float l = l0 * ex2(m0 - m) + l1 * ex2(m1 - m);
        Ms[(size_t)bh * L_ + kbase + tid] = m;
        Rl[(size_t)bh * L_ + kbase + tid] = 1.0f / l;
    }
}

// ---------------------------------------------------------------------------
// V transpose + fold 1/l: vt[bh][d][l] = vb[b][l][h*64+d] * Rl[bh][l]
// ---------------------------------------------------------------------------
__global__ __launch_bounds__(256) void transpose_v_scaled(
    const u16* __restrict__ Vb, const float* __restrict__ Rl,
    u16* __restrict__ Vt)
{
    const int l0 = blockIdx.x * 64, h = blockIdx.y, b = blockIdx.z;
    const int bh = b * NH_ + h;
    __shared__ __align__(16) u16 Ts[64][72];
    const int tid = threadIdx.x;
    #pragma unroll
    for (int c = tid; c < 512; c += 256) {
        int r = c >> 3, cc = c & 7;
        u16x8 val = *(const u16x8*)(Vb + (size_t)(b * L_ + l0 + r) * D_ + h * HD_ + cc * 8);
        const float rl = Rl[(size_t)bh * L_ + l0 + r];
        #pragma unroll
        for (int e = 0; e < 8; ++e) val[e] = f2bf(bf2f(val[e]) * rl);
        *(u16x8*)(&Ts[r][cc * 8]) = val;
    }
    __syncthreads();
    const int d = tid >> 2, lc = (tid & 3) * 16;
    u16 tmp[16];
    #pragma unroll
    for (int e = 0; e < 16; ++e) tmp[e] = Ts[lc + e][d];
    u16x8 o0, o1;
    #pragma unroll
    for (int e = 0; e < 8; ++e) { o0[e] = tmp[e]; o1[e] = tmp[8 + e]; }
    u16* dst = Vt + ((size_t)bh * HD_ + d) * L_ + l0 + lc;
    *(u16x8*)dst = o0;
    *(u16x8*)(dst + 8) = o1;
}

// ---------------------------------------------------------------------------
// Pass B: O = P·V' with P[q,k] = exp2(s2 - m[k]), V' = V*rl (pre-folded).
// Block: 128 queries; loops 64-key tiles. Q frags hoisted; Qs LDS reused as P.
// All stride-64 tiles XOR-swizzled.
// ---------------------------------------------------------------------------
__global__ __launch_bounds__(256) void attn_out(
    const u16* __restrict__ Qb, const u16* __restrict__ Kb,
    const u16* __restrict__ Vt, const float* __restrict__ Ms,
    u16* __restrict__ Ob)
{
    __shared__ __align__(16) u16 QsP[128 * 64];  // 16 KB: Q staging, then P
    __shared__ __align__(16) u16 Ks[64 * 64];    //  8 KB
    __shared__ __align__(16) u16 Vts[64 * 64];   //  8 KB
    __shared__ __align__(16) float mch[64];
    const int tid  = threadIdx.x;
    const int lane = tid & 63, w = tid >> 6;
    const int s    = lane & 15, quad = lane >> 4;
    const int s7   = s & 7;
    const int bh   = blockIdx.y;
    const int b    = bh / NH_, h = bh % NH_;
    const int qbase = blockIdx.x * 128;
    const u16* Qg = Qb + (size_t)b * L_ * D_ + h * HD_;
    const u16* Kg = Kb + (size_t)b * L_ * D_ + h * HD_;
    const u16* Vg = Vt + (size_t)bh * HD_ * L_;     // [64 d][2048 l], pre-scaled
    const float* Mg = Ms + (size_t)bh * L_;
    const int qh  = (w >> 1) * 64;   // query half (both phases)
    const int kh2 = (w & 1) * 32;    // key sub-tile (S phase)
    const int dh  = (w & 1) * 32;    // d sub-tile (PV phase)
    const int wb  = tid & ~63;

    // stage Q tile (XOR-swizzled source)
    #pragma unroll
    for (int c0 = 0; c0 < 1024; c0 += 256) {
        int c = c0 + tid, r = c >> 3, cc = (c & 7) ^ (r & 7);
        gld16(Qg + (size_t)(qbase + r) * D_ + cc * 8, QsP + (size_t)(c0 + wb) * 8);
    }
    __syncthreads();
    // hoist Q fragments (loop-invariant); QsP then becomes the P buffer
    bf16x8 qf[2][4];
    #pragma unroll
    for (int kk = 0; kk < 2; ++kk)
        #pragma unroll
        for (int j = 0; j < 4; ++j)
            qf[kk][j] = *(const bf16x8*)(QsP + (qh + j * 16 + s) * 64 +
                                         ((kk * 4 + quad) ^ s7) * 8);

    f32x4 acc_o[2][4];
    #pragma unroll
    for (int i = 0; i < 2; ++i)
        #pragma unroll
        for (int j = 0; j < 4; ++j) acc_o[i][j] = (f32x4){0.f, 0.f, 0.f, 0.f};

    for (int k0 = 0; k0 < L_; k0 += 64) {
        // stage K and V' tiles (XOR-swizzled sources)
        {
            int c = tid, r = c >> 3, cc = (c & 7) ^ (r & 7);
            gld16(Kg + (size_t)(k0 + r) * D_ + cc * 8, Ks + (size_t)wb * 8);
            gld16(Vg + (size_t)r * L_ + k0 + cc * 8,   Vts + (size_t)wb * 8);
            c = tid + 256; r = c >> 3; cc = (c & 7) ^ (r & 7);
            gld16(Kg + (size_t)(k0 + r) * D_ + cc * 8, Ks + (size_t)(wb + 256) * 8);
            gld16(Vg + (size_t)r * L_ + k0 + cc * 8,   Vts + (size_t)(wb + 256) * 8);
        }
        if (tid < 64) mch[tid] = Mg[k0 + tid];
        __syncthreads();   // staging done; prev-iter P reads done (barrier B)
        // ---- S^T: 32 keys x 64 queries per wave ----
        f32x4 acc_s[2][4];
        #pragma unroll
        for (int i = 0; i < 2; ++i)
            #pragma unroll
            for (int j = 0; j < 4; ++j) acc_s[i][j] = (f32x4){0.f, 0.f, 0.f, 0.f};
        #pragma unroll
        for (int kk = 0; kk < 2; ++kk) {
            bf16x8 af[2];
            #pragma unroll
            for (int i = 0; i < 2; ++i)
                af[i] = *(const bf16x8*)(Ks + (kh2 + i * 16 + s) * 64 +
                                         ((kk * 4 + quad) ^ s7) * 8);
            #pragma unroll
            for (int i = 0; i < 2; ++i)
                #pragma unroll
                for (int j = 0; j < 4; ++j)
                    acc_s[i][j] = __builtin_amdgcn_mfma_f32_16x16x32_bf16(
                        af[i], qf[kk][j], acc_s[i][j], 0, 0, 0);
        }
        // ---- P[q][k] = exp2(fma(s, SC2, -m)), swizzled write ----
        #pragma unroll
        for (int i = 0; i < 2; ++i) {
            const int kb_ = kh2 + i * 16 + quad * 4;
            f32x4 mv = *(const f32x4*)(mch + kb_);
            const int pchunk = (kb_ >> 3), poff = kb_ & 7;
            #pragma unroll
            for (int j = 0; j < 4; ++j) {
                const int q = qh + j * 16 + s;
                u16x4 pk;
                #pragma unroll
                for (int r = 0; r < 4; ++r)
                    pk[r] = f2bf_ru(ex2(fmaf(acc_s[i][j][r], SC2, -mv[r])));
                *(u16x4*)(QsP + q * 64 + (pchunk ^ s7) * 8 + poff) = pk;
            }
        }
        __syncthreads();   // P visible (barrier A)
        // ---- O^T += V'^T · P^T : 32 d x 64 q per wave ----
        #pragma unroll
        for (int kk = 0; kk < 2; ++kk) {
            bf16x8 av[2], bp[4];
            #pragma unroll
            for (int i = 0; i < 2; ++i)
                av[i] = *(const bf16x8*)(Vts + (dh + i * 16 + s) * 64 +
                                         ((kk * 4 + quad) ^ s7) * 8);
            #pragma unroll
            for (int j = 0; j < 4; ++j)
                bp[j] = *(const bf16x8*)(QsP + (qh + j * 16 + s) * 64 +
                                         ((kk * 4 + quad) ^ s7) * 8);
            #pragma unroll
            for (int i = 0; i < 2; ++i)
                #pragma unroll
                for (int j = 0; j < 4; ++j)
                    acc_o[i][j] = __builtin_amdgcn_mfma_f32_16x16x32_bf16(
                        av[i], bp[j], acc_o[i][j], 0, 0, 0);
        }
        // next iter's barrier-after-staging doubles as the P/K/V read fence
        __syncthreads();
    }
    // ---- epilogue: O^T -> LDS (QsP as [q][64] swizzled) -> coalesced store
    #pragma unroll
    for (int i = 0; i < 2; ++i) {
        const int d0 = dh + i * 16 + quad * 4;
        const int dchunk = d0 >> 3, doff = d0 & 7;
        #pragma unroll
        for (int j = 0; j < 4; ++j) {
            const int q = qh + j * 16 + s;
            u16x4 ov;
            #pragma unroll
            for (int r = 0; r < 4; ++r) ov[r] = f2bf(acc_o[i][j][r]);
            *(u16x4*)(QsP + q * 64 + (dchunk ^ s7) * 8 + doff) = ov;
        }
    }
    __syncthreads();
    {
        const int q = tid >> 1, half = tid & 1, q7 = q & 7;
        u16* dst = Ob + (size_t)(b * L_ + qbase + q) * D_ + h * HD_ + half * 32;
        #pragma unroll
        for (int c = 0; c < 4; ++c) {
            u16x8 v = *(const u16x8*)(QsP + q * 64 + ((half * 4 + c) ^ q7) * 8);
            *(u16x8*)(dst + c * 8) = v;
        }
    }
}

// ---------------------------------------------------------------------------
extern "C" void kernel_launch(void* const* d_in, const int* in_sizes, int n_in,
                              void* d_out, int out_size, void* d_ws, size_t ws_size,
                              hipStream_t stream)
{
    const float* x  = (const float*)d_in[0];
    const float* Wq = (const float*)d_in[1];
    const float* Wk = (const float*)d_in[2];
    const float* bk = (const float*)d_in[3];
    const float* Wv = (const float*)d_in[4];
    const float* bv = (const float*)d_in[5];
    const float* gq = (const float*)d_in[6];
    const float* gk = (const float*)d_in[7];
    const float* Wo = (const float*)d_in[8];
    const float* bo = (const float*)d_in[9];
    float* out = (float*)d_out;

    char* p = (char*)d_ws;
    float* q32 = (float*)p;  p += (size_t)M_ * D_ * 4;    // ob aliases after LN
    float* k32 = (float*)p;  p += (size_t)M_ * D_ * 4;    // vt aliases after LN
    u16* xb  = (u16*)p;      p += (size_t)M_ * D_ * 2;
    u16* qb  = (u16*)p;      p += (size_t)M_ * D_ * 2;
    u16* kb  = (u16*)p;      p += (size_t)M_ * D_ * 2;
    u16* vb  = (u16*)p;      p += (size_t)M_ * D_ * 2;
    u16* wqb = (u16*)p;      p += (size_t)D_ * D_ * 2;
    u16* wkb = (u16*)p;      p += (size_t)D_ * D_ * 2;
    u16* wvb = (u16*)p;      p += (size_t)D_ * D_ * 2;
    u16* wob = (u16*)p;      p += (size_t)D_ * D_ * 2;
    float* Ms = (float*)p;   p += (size_t)B_ * NH_ * L_ * 4;
    float* Rl = (float*)p;   p += (size_t)B_ * NH_ * L_ * 4;
    u16* ob = (u16*)q32;
    u16* vt = (u16*)k32;

    const int nX = M_ * D_, nW = D_ * D_;
    cvt_bf16_kernel<<<nX / 2048, 256, 0, stream>>>(x, xb, nX / 8);
    cvt4_bf16_kernel<<<dim3(nW / 2048, 4), 256, 0, stream>>>(
        Wq, Wk, Wv, Wo, wqb, wkb, wvb, wob, nW / 8);

    gemm_qkv<<<dim3(18, M_ / 128), 256, 0, stream>>>(
        xb, wqb, wkb, wvb, bk, bv, q32, k32, vb);

    ln_bf16<<<M_, 256, 0, stream>>>(q32, gq, qb);
    ln_bf16<<<M_, 256, 0, stream>>>(k32, gk, kb);

    dim3 agrid(L_ / 128, B_ * NH_);   // (16, 48)
    attn_stats<<<agrid, 256, 0, stream>>>(qb, kb, Ms, Rl);
    transpose_v_scaled<<<dim3(L_ / 64, NH_, B_), 256, 0, stream>>>(vb, Rl, vt);
    attn_out<<<agrid, 256, 0, stream>>>(qb, kb, vt, Ms, ob);

    gemm_final<<<dim3(D_ / 128, M_ / 128), 256, 0, stream>>>(ob, wob, bo, x, out);
}

// Round 5
// 314.756 us; speedup vs baseline: 9.1242x; 1.0765x over previous
//
#include <hip/hip_runtime.h>
#include <cstddef>
#include <cstdint>

// ---------------------------------------------------------------------------
// MultiheadSelfAttn (b=4, l=2048, d=768, nh=12, hd=64), softmax over QUERY axis.
// bf16-MFMA pipeline: cvt -> fused QKV GEMM -> LN(->bf16, SC2 folded into q) ->
// stats (no-max exp2 sum; QK-norm bounds scores) -> V transpose (*1/l folded,
// key-permuted within 32-groups) -> attention out (register-P: S C-layout ->
// PV B-frags as pure same-lane register renames; K/V LDS double-buffered,
// ONE barrier per k-iter) -> final GEMM.
// ---------------------------------------------------------------------------

typedef unsigned short u16;
typedef short  bf16x8 __attribute__((ext_vector_type(8)));   // MFMA A/B frag
typedef float  f32x4  __attribute__((ext_vector_type(4)));   // MFMA C/D frag
typedef unsigned short u16x8 __attribute__((ext_vector_type(8)));
typedef unsigned short u16x4 __attribute__((ext_vector_type(4)));

#define B_   4
#define L_   2048
#define D_   768
#define NH_  12
#define HD_  64
#define M_   (B_*L_)
#define SC2  (0.125f * 1.44269504088896f)   // scale * log2(e), folded into qb

__device__ __forceinline__ float ex2(float x) { return __builtin_amdgcn_exp2f(x); }

__device__ __forceinline__ u16 f2bf(float f) {            // RNE
    union { float f; unsigned u; } v; v.f = f;
    unsigned r = v.u + 0x7FFFu + ((v.u >> 16) & 1u);
    return (u16)(r >> 16);
}
__device__ __forceinline__ float bf2f(u16 b) {
    union { unsigned u; float f; } v; v.u = ((unsigned)b) << 16;
    return v.f;
}
__device__ __forceinline__ unsigned fbits(float f) {
    union { float f; unsigned u; } v; v.f = f; return v.u;
}
// pack two f32 -> (bf16(lo) | bf16(hi)<<16), truncation (P>=0, slack ok)
__device__ __forceinline__ unsigned packbf(float lo, float hi) {
    return __builtin_amdgcn_perm(fbits(hi), fbits(lo), 0x07060302u);
}

// async global->LDS, 16B/lane; LDS dest = wave-uniform base + lane*16.
__device__ __forceinline__ void gld16(const void* g, void* l) {
    __builtin_amdgcn_global_load_lds(
        (const __attribute__((address_space(1))) unsigned*)g,
        (__attribute__((address_space(3))) unsigned*)l, 16, 0, 0);
}

// ---------------------------------------------------------------------------
// fp32 -> bf16 bulk convert
// ---------------------------------------------------------------------------
__global__ __launch_bounds__(256) void cvt_bf16_kernel(
    const float* __restrict__ X, u16* __restrict__ Y, int n8)
{
    int i = blockIdx.x * 256 + threadIdx.x;
    if (i >= n8) return;
    const float4* xp = (const float4*)X + (size_t)i * 2;
    float4 a = xp[0], b = xp[1];
    u16x8 o;
    o[0] = f2bf(a.x); o[1] = f2bf(a.y); o[2] = f2bf(a.z); o[3] = f2bf(a.w);
    o[4] = f2bf(b.x); o[5] = f2bf(b.y); o[6] = f2bf(b.z); o[7] = f2bf(b.w);
    *((u16x8*)Y + i) = o;
}

__global__ __launch_bounds__(256) void cvt4_bf16_kernel(
    const float* __restrict__ W0, const float* __restrict__ W1,
    const float* __restrict__ W2, const float* __restrict__ W3,
    u16* __restrict__ Y0, u16* __restrict__ Y1,
    u16* __restrict__ Y2, u16* __restrict__ Y3, int n8)
{
    const float* X; u16* Y;
    switch (blockIdx.y) {
        case 0: X = W0; Y = Y0; break;
        case 1: X = W1; Y = Y1; break;
        case 2: X = W2; Y = Y2; break;
        default: X = W3; Y = Y3; break;
    }
    int i = blockIdx.x * 256 + threadIdx.x;
    if (i >= n8) return;
    const float4* xp = (const float4*)X + (size_t)i * 2;
    float4 a = xp[0], b = xp[1];
    u16x8 o;
    o[0] = f2bf(a.x); o[1] = f2bf(a.y); o[2] = f2bf(a.z); o[3] = f2bf(a.w);
    o[4] = f2bf(b.x); o[5] = f2bf(b.y); o[6] = f2bf(b.z); o[7] = f2bf(b.w);
    *((u16x8*)Y + i) = o;
}

// ---------------------------------------------------------------------------
// Fused QKV GEMM: A[8192,768] x {Wq,Wk,Wv}^T. 128x128 tile, BK=32.
// ---------------------------------------------------------------------------
__global__ __launch_bounds__(256) void gemm_qkv(
    const u16* __restrict__ A,
    const u16* __restrict__ W0, const u16* __restrict__ W1,
    const u16* __restrict__ W2,
    const float* __restrict__ bk, const float* __restrict__ bv,
    float* __restrict__ q32, float* __restrict__ k32, u16* __restrict__ vb)
{
    __shared__ __align__(16) u16 As[128 * 32];
    __shared__ __align__(16) u16 Bs[128 * 32];
    const int tid  = threadIdx.x;
    const int lane = tid & 63, w = tid >> 6;
    const int s    = lane & 15, quad = lane >> 4;
    const int seg  = blockIdx.x / 6;
    const int bn   = (blockIdx.x % 6) * 128;
    const int bm   = blockIdx.y * 128;
    const u16* W = (seg == 0) ? W0 : ((seg == 1) ? W1 : W2);
    const int mh = (w >> 1) * 64, nh = (w & 1) * 64;
    const int wb = tid & ~63;
    f32x4 acc[4][4];
    #pragma unroll
    for (int i = 0; i < 4; ++i)
        #pragma unroll
        for (int j = 0; j < 4; ++j) acc[i][j] = (f32x4){0.f, 0.f, 0.f, 0.f};

    for (int k0 = 0; k0 < D_; k0 += 32) {
        {
            int c = tid, r = c >> 2, cc = c & 3;
            gld16(A + (size_t)(bm + r) * D_ + k0 + cc * 8, As + (size_t)wb * 8);
            gld16(W + (size_t)(bn + r) * D_ + k0 + cc * 8, Bs + (size_t)wb * 8);
            c = tid + 256; r = c >> 2; cc = c & 3;
            gld16(A + (size_t)(bm + r) * D_ + k0 + cc * 8, As + (size_t)(wb + 256) * 8);
            gld16(W + (size_t)(bn + r) * D_ + k0 + cc * 8, Bs + (size_t)(wb + 256) * 8);
        }
        __syncthreads();
        bf16x8 af[4], bf[4];
        #pragma unroll
        for (int i = 0; i < 4; ++i)
            af[i] = *(const bf16x8*)(As + (mh + i * 16 + s) * 32 + quad * 8);
        #pragma unroll
        for (int j = 0; j < 4; ++j)
            bf[j] = *(const bf16x8*)(Bs + (nh + j * 16 + s) * 32 + quad * 8);
        #pragma unroll
        for (int i = 0; i < 4; ++i)
            #pragma unroll
            for (int j = 0; j < 4; ++j)
                acc[i][j] = __builtin_amdgcn_mfma_f32_16x16x32_bf16(
                    af[i], bf[j], acc[i][j], 0, 0, 0);
        __syncthreads();
    }
    #pragma unroll
    for (int j = 0; j < 4; ++j) {
        const int n = bn + nh + j * 16 + s;
        float bb = 0.0f;
        if (seg == 1) bb = bk[n];
        else if (seg == 2) bb = bv[n];
        #pragma unroll
        for (int i = 0; i < 4; ++i) {
            const int m0 = bm + mh + i * 16 + quad * 4;
            #pragma unroll
            for (int r = 0; r < 4; ++r) {
                float y = acc[i][j][r] + bb;
                const size_t idx = (size_t)(m0 + r) * D_ + n;
                if (seg == 0)      q32[idx] = y;
                else if (seg == 1) k32[idx] = y;
                else               vb[idx]  = f2bf(y);
            }
        }
    }
}

// ---------------------------------------------------------------------------
// Final GEMM: out = ob @ Wo^T + bo + x (fp32 out)
// ---------------------------------------------------------------------------
__global__ __launch_bounds__(256) void gemm_final(
    const u16* __restrict__ A, const u16* __restrict__ W,
    const float* __restrict__ bias, const float* __restrict__ resid,
    float* __restrict__ outf)
{
    __shared__ __align__(16) u16 As[128 * 32];
    __shared__ __align__(16) u16 Bs[128 * 32];
    const int tid  = threadIdx.x;
    const int lane = tid & 63, w = tid >> 6;
    const int s    = lane & 15, quad = lane >> 4;
    const int bm   = blockIdx.y * 128, bn = blockIdx.x * 128;
    const int mh   = (w >> 1) * 64, nh = (w & 1) * 64;
    const int wb   = tid & ~63;
    f32x4 acc[4][4];
    #pragma unroll
    for (int i = 0; i < 4; ++i)
        #pragma unroll
        for (int j = 0; j < 4; ++j) acc[i][j] = (f32x4){0.f, 0.f, 0.f, 0.f};

    for (int k0 = 0; k0 < D_; k0 += 32) {
        {
            int c = tid, r = c >> 2, cc = c & 3;
            gld16(A + (size_t)(bm + r) * D_ + k0 + cc * 8, As + (size_t)wb * 8);
            gld16(W + (size_t)(bn + r) * D_ + k0 + cc * 8, Bs + (size_t)wb * 8);
            c = tid + 256; r = c >> 2; cc = c & 3;
            gld16(A + (size_t)(bm + r) * D_ + k0 + cc * 8, As + (size_t)(wb + 256) * 8);
            gld16(W + (size_t)(bn + r) * D_ + k0 + cc * 8, Bs + (size_t)(wb + 256) * 8);
        }
        __syncthreads();
        bf16x8 af[4], bf[4];
        #pragma unroll
        for (int i = 0; i < 4; ++i)
            af[i] = *(const bf16x8*)(As + (mh + i * 16 + s) * 32 + quad * 8);
        #pragma unroll
        for (int j = 0; j < 4; ++j)
            bf[j] = *(const bf16x8*)(Bs + (nh + j * 16 + s) * 32 + quad * 8);
        #pragma unroll
        for (int i = 0; i < 4; ++i)
            #pragma unroll
            for (int j = 0; j < 4; ++j)
                acc[i][j] = __builtin_amdgcn_mfma_f32_16x16x32_bf16(
                    af[i], bf[j], acc[i][j], 0, 0, 0);
        __syncthreads();
    }
    #pragma unroll
    for (int j = 0; j < 4; ++j) {
        const int n = bn + nh + j * 16 + s;
        const float bb = bias[n];
        #pragma unroll
        for (int i = 0; i < 4; ++i) {
            const int m0 = bm + mh + i * 16 + quad * 4;
            #pragma unroll
            for (int r = 0; r < 4; ++r) {
                const size_t idx = (size_t)(m0 + r) * D_ + n;
                outf[idx] = acc[i][j][r] + bb + resid[idx];
            }
        }
    }
}

// ---------------------------------------------------------------------------
// Row LayerNorm (pop var, eps 1e-5) * gamma * scale, fp32 in -> bf16 out.
// scale = SC2 for q (folds softmax scale+log2e), 1.0 for k.
// ---------------------------------------------------------------------------
__global__ __launch_bounds__(256) void ln_bf16(
    const float* __restrict__ X, const float* __restrict__ gamma,
    u16* __restrict__ Y, float scale)
{
    const int row = blockIdx.x;
    const float* x = X + (size_t)row * D_;
    const int tid = threadIdx.x;
    float v[3];
    float lsum = 0.f, lsq = 0.f;
    #pragma unroll
    for (int e = 0; e < 3; ++e) {
        float t = x[tid + e * 256];
        v[e] = t; lsum += t; lsq += t * t;
    }
    #pragma unroll
    for (int off = 32; off > 0; off >>= 1) {
        lsum += __shfl_down(lsum, off);
        lsq  += __shfl_down(lsq,  off);
    }
    __shared__ float s1[4], s2[4];
    const int wv = tid >> 6, lane = tid & 63;
    if (lane == 0) { s1[wv] = lsum; s2[wv] = lsq; }
    __syncthreads();
    const float sum = s1[0] + s1[1] + s1[2] + s1[3];
    const float sq  = s2[0] + s2[1] + s2[2] + s2[3];
    const float mu  = sum * (1.0f / D_);
    const float var = sq * (1.0f / D_) - mu * mu;
    const float inv = rsqrtf(var + 1e-5f) * scale;
    #pragma unroll
    for (int e = 0; e < 3; ++e) {
        int c = tid + e * 256;
        Y[(size_t)row * D_ + c] = f2bf((v[e] - mu) * inv * gamma[c]);
    }
}

// ---------------------------------------------------------------------------
// Pass A: per-key l = sum_q exp2(s~[q,k]) (NO max: QK-norm bounds scores).
// Block: 128 keys; K frags hoisted; Q staging double-buffered, 1 barrier/iter.
// ---------------------------------------------------------------------------
__global__ __launch_bounds__(256) void attn_stats(
    const u16* __restrict__ Qb, const u16* __restrict__ Kb,
    float* __restrict__ Rl)
{
    __shared__ __align__(16) u16 Ks[128 * 64];       // 16 KB
    __shared__ __align__(16) u16 Qs[2][128 * 64];    // 32 KB dbuf
    __shared__ float lbuf[4][64];
    const int tid  = threadIdx.x;
    const int lane = tid & 63, w = tid >> 6;
    const int s    = lane & 15, quad = lane >> 4;
    const int s7   = s & 7;
    const int bh   = blockIdx.y;
    const int b    = bh / NH_, h = bh % NH_;
    const int kbase = blockIdx.x * 128;
    const u16* Qg = Qb + (size_t)b * L_ * D_ + h * HD_;
    const u16* Kg = Kb + (size_t)b * L_ * D_ + h * HD_;
    const int mh = (w >> 1) * 64;   // key half
    const int nh = (w & 1) * 64;    // query half
    const int wb = tid & ~63;

    // stage K tile (swizzled) + Q tile 0
    #pragma unroll
    for (int c0 = 0; c0 < 1024; c0 += 256) {
        int c = c0 + tid, r = c >> 3, cc = (c & 7) ^ (r & 7);
        gld16(Kg + (size_t)(kbase + r) * D_ + cc * 8, Ks + (size_t)(c0 + wb) * 8);
        gld16(Qg + (size_t)r * D_ + cc * 8, Qs[0] + (size_t)(c0 + wb) * 8);
    }
    __syncthreads();
    // hoist K A-frags (loop-invariant)
    bf16x8 kf[2][4];
    #pragma unroll
    for (int kk = 0; kk < 2; ++kk)
        #pragma unroll
        for (int i = 0; i < 4; ++i)
            kf[kk][i] = *(const bf16x8*)(Ks + (mh + i * 16 + s) * 64 +
                                         ((kk * 4 + quad) ^ s7) * 8);
    float lacc[4][4];
    #pragma unroll
    for (int i = 0; i < 4; ++i)
        #pragma unroll
        for (int r = 0; r < 4; ++r) lacc[i][r] = 0.f;

    for (int t = 0; t < 16; ++t) {
        if (t < 15) {
            const int qn = (t + 1) * 128;
            u16* Qd = Qs[(t + 1) & 1];
            #pragma unroll
            for (int c0 = 0; c0 < 1024; c0 += 256) {
                int c = c0 + tid, r = c >> 3, cc = (c & 7) ^ (r & 7);
                gld16(Qg + (size_t)(qn + r) * D_ + cc * 8, Qd + (size_t)(c0 + wb) * 8);
            }
        }
        const u16* Qt = Qs[t & 1];
        f32x4 acc[4][4];
        #pragma unroll
        for (int i = 0; i < 4; ++i)
            #pragma unroll
            for (int j = 0; j < 4; ++j) acc[i][j] = (f32x4){0.f, 0.f, 0.f, 0.f};
        #pragma unroll
        for (int kk = 0; kk < 2; ++kk) {
            bf16x8 bf[4];
            #pragma unroll
            for (int j = 0; j < 4; ++j)
                bf[j] = *(const bf16x8*)(Qt + (nh + j * 16 + s) * 64 +
                                         ((kk * 4 + quad) ^ s7) * 8);
            #pragma unroll
            for (int i = 0; i < 4; ++i)
                #pragma unroll
                for (int j = 0; j < 4; ++j)
                    acc[i][j] = __builtin_amdgcn_mfma_f32_16x16x32_bf16(
                        kf[kk][i], bf[j], acc[i][j], 0, 0, 0);
        }
        // exp2-sum (no max)
        #pragma unroll
        for (int i = 0; i < 4; ++i)
            #pragma unroll
            for (int r = 0; r < 4; ++r) {
                float l0 = ex2(acc[i][0][r]) + ex2(acc[i][1][r]);
                float l1 = ex2(acc[i][2][r]) + ex2(acc[i][3][r]);
                lacc[i][r] += l0 + l1;
            }
        __syncthreads();
    }
    // butterfly-sum over the 16 s-lanes within each quad
    #pragma unroll
    for (int i = 0; i < 4; ++i)
        #pragma unroll
        for (int r = 0; r < 4; ++r) {
            float v = lacc[i][r];
            #pragma unroll
            for (int d2 = 1; d2 < 16; d2 <<= 1) v += __shfl_xor(v, d2);
            lacc[i][r] = v;
        }
    if (s == 0) {
        #pragma unroll
        for (int i = 0; i < 4; ++i)
            #pragma unroll
            for (int r = 0; r < 4; ++r)
                lbuf[w][i * 16 + quad * 4 + r] = lacc[i][r];
    }
    __syncthreads();
    if (tid < 128) {
        int kh = tid >> 6, kl = tid & 63;
        float l = lbuf[kh * 2][kl] + lbuf[kh * 2 + 1][kl];
        Rl[(size_t)bh * L_ + kbase + tid] = 1.0f / l;
    }
}

// ---------------------------------------------------------------------------
// V transpose + fold 1/l + PV key-permutation:
// within each 32-l group, actual key a is stored at
//   p = ((a>>2)&3)*8 + ((a>>4)&1)*4 + (a&3)
// so that attn_out's PV B-frags are pure register renames of the S output.
// ---------------------------------------------------------------------------
__global__ __launch_bounds__(256) void transpose_v_scaled(
    const u16* __restrict__ Vb, const float* __restrict__ Rl,
    u16* __restrict__ Vt)
{
    const int l0 = blockIdx.x * 64, h = blockIdx.y, b = blockIdx.z;
    const int bh = b * NH_ + h;
    __shared__ __align__(16) u16 Ts[64][72];
    const int tid = threadIdx.x;
    #pragma unroll
    for (int c = tid; c < 512; c += 256) {
        int r = c >> 3, cc = c & 7;
        u16x8 val = *(const u16x8*)(Vb + (size_t)(b * L_ + l0 + r) * D_ + h * HD_ + cc * 8);
        const float rl = Rl[(size_t)bh * L_ + l0 + r];
        #pragma unroll
        for (int e = 0; e < 8; ++e) val[e] = f2bf(bf2f(val[e]) * rl);
        *(u16x8*)(&Ts[r][cc * 8]) = val;
    }
    __syncthreads();
    const int d = tid >> 2, lc = (tid & 3) * 16;
    u16 tmp[16];
    #pragma unroll
    for (int e = 0; e < 16; ++e) tmp[e] = Ts[lc + e][d];
    // permuted write: 4 x u16x4 runs
    u16* dst = Vt + ((size_t)bh * HD_ + d) * L_ + l0 + (lc & 32) + ((lc >> 4) & 1) * 4;
    #pragma unroll
    for (int qd = 0; qd < 4; ++qd) {
        u16x4 o;
        #pragma unroll
        for (int e = 0; e < 4; ++e) o[e] = tmp[qd * 4 + e];
        *(u16x4*)(dst + qd * 8) = o;
    }
}

// ---------------------------------------------------------------------------
// Pass B: O^T = V'^T · P^T, P = exp2(s~) (rl pre-folded into V').
// Block: 256 queries; wave = full 64 d x 64-query quarter; k-tile 64.
// P stays in registers (V key-permutation makes PV B-frags same-lane renames
// of the packed S output). K/V double-buffered, one barrier per iter.
// ---------------------------------------------------------------------------
__global__ __launch_bounds__(256, 2) void attn_out(
    const u16* __restrict__ Qb, const u16* __restrict__ Kb,
    const u16* __restrict__ Vt, u16* __restrict__ Ob)
{
    __shared__ __align__(16) u16 Qs[256 * 64];     // 32 KB: Q staging -> O epilogue
    __shared__ __align__(16) u16 Ks[2][64 * 64];   // 16 KB dbuf
    __shared__ __align__(16) u16 Vts[2][64 * 64];  // 16 KB dbuf
    const int tid  = threadIdx.x;
    const int lane = tid & 63, w = tid >> 6;
    const int s    = lane & 15, quad = lane >> 4;
    const int s7   = s & 7;
    const int bh   = blockIdx.y;
    const int b    = bh / NH_, h = bh % NH_;
    const int qbase = blockIdx.x * 256;
    const int qw   = w * 64;
    const u16* Qg = Qb + (size_t)b * L_ * D_ + h * HD_;
    const u16* Kg = Kb + (size_t)b * L_ * D_ + h * HD_;
    const u16* Vg = Vt + (size_t)bh * HD_ * L_;   // [64 d][2048 l'], permuted+scaled
    const int wb = tid & ~63;

    // stage Q (2048 chunks, 8/thread) + preload K/V tile 0
    #pragma unroll
    for (int c0 = 0; c0 < 2048; c0 += 256) {
        int c = c0 + tid, r = c >> 3, cc = (c & 7) ^ (r & 7);
        gld16(Qg + (size_t)(qbase + r) * D_ + cc * 8, Qs + (size_t)(c0 + wb) * 8);
    }
    {
        int c = tid, r = c >> 3, cc = (c & 7) ^ (r & 7);
        gld16(Kg + (size_t)r * D_ + cc * 8, Ks[0] + (size_t)wb * 8);
        gld16(Vg + (size_t)r * L_ + cc * 8, Vts[0] + (size_t)wb * 8);
        c = tid + 256; r = c >> 3; cc = (c & 7) ^ (r & 7);
        gld16(Kg + (size_t)r * D_ + cc * 8, Ks[0] + (size_t)(wb + 256) * 8);
        gld16(Vg + (size_t)r * L_ + cc * 8, Vts[0] + (size_t)(wb + 256) * 8);
    }
    __syncthreads();
    // hoist Q B-frags (loop-invariant)
    bf16x8 qf[2][4];
    #pragma unroll
    for (int kk = 0; kk < 2; ++kk)
        #pragma unroll
        for (int j = 0; j < 4; ++j)
            qf[kk][j] = *(const bf16x8*)(Qs + (qw + j * 16 + s) * 64 +
                                         ((kk * 4 + quad) ^ s7) * 8);
    f32x4 acc_o[4][4];
    #pragma unroll
    for (int i = 0; i < 4; ++i)
        #pragma unroll
        for (int j = 0; j < 4; ++j) acc_o[i][j] = (f32x4){0.f, 0.f, 0.f, 0.f};

    for (int t = 0; t < 32; ++t) {
        const u16* Kt  = Ks[t & 1];
        const u16* Vtt = Vts[t & 1];
        if (t < 31) {   // prefetch next tile (lands during compute below)
            const int kn = (t + 1) * 64;
            u16* Kd = Ks[(t + 1) & 1];
            u16* Vd = Vts[(t + 1) & 1];
            int c = tid, r = c >> 3, cc = (c & 7) ^ (r & 7);
            gld16(Kg + (size_t)(kn + r) * D_ + cc * 8, Kd + (size_t)wb * 8);
            gld16(Vg + (size_t)r * L_ + kn + cc * 8,   Vd + (size_t)wb * 8);
            c = tid + 256; r = c >> 3; cc = (c & 7) ^ (r & 7);
            gld16(Kg + (size_t)(kn + r) * D_ + cc * 8, Kd + (size_t)(wb + 256) * 8);
            gld16(Vg + (size_t)r * L_ + kn + cc * 8,   Vd + (size_t)(wb + 256) * 8);
        }
        // ---- S: 64 keys x 64 queries (this wave's quarter) ----
        f32x4 acc_s[4][4];
        #pragma unroll
        for (int i = 0; i < 4; ++i)
            #pragma unroll
            for (int j = 0; j < 4; ++j) acc_s[i][j] = (f32x4){0.f, 0.f, 0.f, 0.f};
        #pragma unroll
        for (int kk = 0; kk < 2; ++kk) {
            bf16x8 kfr[4];
            #pragma unroll
            for (int i = 0; i < 4; ++i)
                kfr[i] = *(const bf16x8*)(Kt + (i * 16 + s) * 64 +
                                          ((kk * 4 + quad) ^ s7) * 8);
            #pragma unroll
            for (int i = 0; i < 4; ++i)
                #pragma unroll
                for (int j = 0; j < 4; ++j)
                    acc_s[i][j] = __builtin_amdgcn_mfma_f32_16x16x32_bf16(
                        kfr[i], qf[kk][j], acc_s[i][j], 0, 0, 0);
        }
        // ---- P = exp2(s~), packed bf16 pairs (register only) ----
        unsigned pk[4][4][2];
        #pragma unroll
        for (int i = 0; i < 4; ++i)
            #pragma unroll
            for (int j = 0; j < 4; ++j) {
                float p0 = ex2(acc_s[i][j][0]), p1 = ex2(acc_s[i][j][1]);
                float p2 = ex2(acc_s[i][j][2]), p3 = ex2(acc_s[i][j][3]);
                pk[i][j][0] = packbf(p0, p1);
                pk[i][j][1] = packbf(p2, p3);
            }
        // ---- O^T += V'^T · P^T (B-frags = register renames of pk) ----
        #pragma unroll
        for (int kk = 0; kk < 2; ++kk) {
            bf16x8 av[4];
            #pragma unroll
            for (int i = 0; i < 4; ++i)
                av[i] = *(const bf16x8*)(Vtt + (i * 16 + s) * 64 +
                                         ((kk * 4 + quad) ^ s7) * 8);
            #pragma unroll
            for (int j = 0; j < 4; ++j) {
                union { unsigned u[4]; bf16x8 v; } bu;
                bu.u[0] = pk[2 * kk][j][0];
                bu.u[1] = pk[2 * kk][j][1];
                bu.u[2] = pk[2 * kk + 1][j][0];
                bu.u[3] = pk[2 * kk + 1][j][1];
                #pragma unroll
                for (int i = 0; i < 4; ++i)
                    acc_o[i][j] = __builtin_amdgcn_mfma_f32_16x16x32_bf16(
                        av[i], bu.v, acc_o[i][j], 0, 0, 0);
            }
        }
        __syncthreads();   // staging(t+1) done + all K/V(t) reads done
    }
    // ---- epilogue: O^T -> Qs as [256 q][64 d] (swizzled) -> coalesced store
    #pragma unroll
    for (int i = 0; i < 4; ++i) {
        const int d0 = i * 16 + quad * 4;
        const int dchunk = i * 2 + (quad >> 1), doff = (quad & 1) * 4;
        #pragma unroll
        for (int j = 0; j < 4; ++j) {
            const int q = qw + j * 16 + s;
            u16x4 ov;
            #pragma unroll
            for (int r = 0; r < 4; ++r) ov[r] = f2bf(acc_o[i][j][r]);
            *(u16x4*)(Qs + q * 64 + (dchunk ^ s7) * 8 + doff) = ov;
        }
    }
    __syncthreads();
    {
        const int q7 = tid & 7;
        u16* dst = Ob + (size_t)(b * L_ + qbase + tid) * D_ + h * HD_;
        #pragma unroll
        for (int c = 0; c < 8; ++c) {
            u16x8 v = *(const u16x8*)(Qs + tid * 64 + ((c ^ q7) * 8));
            *(u16x8*)(dst + c * 8) = v;
        }
    }
}

// ---------------------------------------------------------------------------
extern "C" void kernel_launch(void* const* d_in, const int* in_sizes, int n_in,
                              void* d_out, int out_size, void* d_ws, size_t ws_size,
                              hipStream_t stream)
{
    const float* x  = (const float*)d_in[0];
    const float* Wq = (const float*)d_in[1];
    const float* Wk = (const float*)d_in[2];
    const float* bk = (const float*)d_in[3];
    const float* Wv = (const float*)d_in[4];
    const float* bv = (const float*)d_in[5];
    const float* gq = (const float*)d_in[6];
    const float* gk = (const float*)d_in[7];
    const float* Wo = (const float*)d_in[8];
    const float* bo = (const float*)d_in[9];
    float* out = (float*)d_out;

    char* p = (char*)d_ws;
    float* q32 = (float*)p;  p += (size_t)M_ * D_ * 4;    // ob aliases after LN
    float* k32 = (float*)p;  p += (size_t)M_ * D_ * 4;    // vt aliases after LN
    u16* xb  = (u16*)p;      p += (size_t)M_ * D_ * 2;
    u16* qb  = (u16*)p;      p += (size_t)M_ * D_ * 2;
    u16* kb  = (u16*)p;      p += (size_t)M_ * D_ * 2;
    u16* vb  = (u16*)p;      p += (size_t)M_ * D_ * 2;
    u16* wqb = (u16*)p;      p += (size_t)D_ * D_ * 2;
    u16* wkb = (u16*)p;      p += (size_t)D_ * D_ * 2;
    u16* wvb = (u16*)p;      p += (size_t)D_ * D_ * 2;
    u16* wob = (u16*)p;      p += (size_t)D_ * D_ * 2;
    float* Rl = (float*)p;   p += (size_t)B_ * NH_ * L_ * 4;
    u16* ob = (u16*)q32;
    u16* vt = (u16*)k32;

    const int nX = M_ * D_, nW = D_ * D_;
    cvt_bf16_kernel<<<nX / 2048, 256, 0, stream>>>(x, xb, nX / 8);
    cvt4_bf16_kernel<<<dim3(nW / 2048, 4), 256, 0, stream>>>(
        Wq, Wk, Wv, Wo, wqb, wkb, wvb, wob, nW / 8);

    gemm_qkv<<<dim3(18, M_ / 128), 256, 0, stream>>>(
        xb, wqb, wkb, wvb, bk, bv, q32, k32, vb);

    ln_bf16<<<M_, 256, 0, stream>>>(q32, gq, qb, SC2);    // softmax scale folded
    ln_bf16<<<M_, 256, 0, stream>>>(k32, gk, kb, 1.0f);

    dim3 sgrid(L_ / 128, B_ * NH_);   // (16, 48)
    attn_stats<<<sgrid, 256, 0, stream>>>(qb, kb, Rl);
    transpose_v_scaled<<<dim3(L_ / 64, NH_, B_), 256, 0, stream>>>(vb, Rl, vt);
    dim3 ogrid(L_ / 256, B_ * NH_);   // (8, 48)
    attn_out<<<ogrid, 256, 0, stream>>>(qb, kb, vt, ob);

    gemm_final<<<dim3(D_ / 128, M_ / 128), 256, 0, stream>>>(ob, wob, bo, x, out);
}